// Round 10
// baseline (1614.733 us; speedup 1.0000x reference)
//
#include <hip/hip_runtime.h>
#include <hip/hip_bf16.h>
#include <math.h>

#define BATCH 64
#define CHUNK 32           // batch chunk for k/v scratch
#define INPUT_SIZE 10080
#define PATCH 18
#define SEQ 560            // S
#define EMB 96             // E
#define NHEAD 12           // H
#define HDIM 96            // D
#define FFDIM 256          // F
#define NLAYER 2
#define TOK (BATCH * SEQ)  // 35840 tokens
#define EPSV 1e-5f
#define SCALE 0.10206207261596577f  // 1/sqrt(96)

typedef __attribute__((ext_vector_type(8))) short bf16x8;  // 8 bf16 (4 VGPRs)
typedef __attribute__((ext_vector_type(4))) short bf16x4;  // 4 bf16 (8B store)
typedef __attribute__((ext_vector_type(4))) float f32x4;   // 4 fp32 acc

static __device__ __forceinline__ short f2bf(float x) {
  union { __hip_bfloat16 b; short s; } u;
  u.b = __float2bfloat16(x);
  return u.s;
}

// ---------------- Kernel 0a: QKV weight transpose prep ---------------------
// wqT:  [L][H][D][E] bf16 ; wkvT: [L][2*H*D][E] bf16 (k rows then v rows)
__global__ __launch_bounds__(256) void wprep_kernel(
    const float* __restrict__ Wq, const float* __restrict__ Wk,
    const float* __restrict__ Wv, __hip_bfloat16* __restrict__ wqT,
    __hip_bfloat16* __restrict__ wkvT) {
  int hh = blockIdx.x, mat = blockIdx.y, l = blockIdx.z;
  const float* src =
      (mat == 0 ? Wq : (mat == 1 ? Wk : Wv)) + ((size_t)l * NHEAD + hh) * EMB * HDIM;
  __shared__ float t[HDIM * 97];
  for (int i = threadIdx.x; i < EMB * HDIM; i += 256) {
    int e = i / HDIM, d = i % HDIM;
    t[d * 97 + e] = src[i];
  }
  __syncthreads();
  __hip_bfloat16* dst;
  if (mat == 0)
    dst = wqT + ((size_t)l * NHEAD + hh) * HDIM * EMB;
  else
    dst = wkvT + ((size_t)l * 2 * NHEAD * HDIM + (mat - 1) * NHEAD * HDIM +
                  hh * HDIM) * EMB;
  for (int j = threadIdx.x; j < HDIM * EMB; j += 256) {
    int d = j / EMB, e = j % EMB;
    dst[j] = __float2bfloat16(t[d * 97 + e]);
  }
}

// ---------------- Kernel 0b: Wo transpose prep -----------------------------
// woT: [L][E=96][HD=1152]   (Wo is [L][1152][96])
__global__ __launch_bounds__(256) void woprep_kernel(
    const float* __restrict__ Wo, __hip_bfloat16* __restrict__ woT) {
  int l = blockIdx.x;
  const float* src = Wo + (size_t)l * NHEAD * HDIM * EMB;
  __hip_bfloat16* dst = woT + (size_t)l * EMB * NHEAD * HDIM;
  for (int i = threadIdx.x; i < EMB * NHEAD * HDIM; i += 256) {
    int e = i / (NHEAD * HDIM), j = i % (NHEAD * HDIM);
    dst[i] = __float2bfloat16(src[(size_t)j * EMB + e]);
  }
}

// ---------------- Kernel 0c: FF weight transpose prep ----------------------
// ff1WT: [L][F=256][E=96]  (ff1_W is [L][96][256]) ; ff2WT: [L][E=96][F=256]
__global__ __launch_bounds__(256) void ffprep_kernel(
    const float* __restrict__ ff1_W, const float* __restrict__ ff2_W,
    __hip_bfloat16* __restrict__ ff1WT, __hip_bfloat16* __restrict__ ff2WT) {
  int mat = blockIdx.x, l = blockIdx.y;
  if (mat == 0) {
    const float* src = ff1_W + (size_t)l * EMB * FFDIM;
    __hip_bfloat16* dst = ff1WT + (size_t)l * FFDIM * EMB;
    for (int i = threadIdx.x; i < FFDIM * EMB; i += 256) {
      int f = i / EMB, e = i % EMB;
      dst[i] = __float2bfloat16(src[(size_t)e * FFDIM + f]);
    }
  } else {
    const float* src = ff2_W + (size_t)l * FFDIM * EMB;
    __hip_bfloat16* dst = ff2WT + (size_t)l * EMB * FFDIM;
    for (int i = threadIdx.x; i < EMB * FFDIM; i += 256) {
      int e = i / FFDIM, f = i % FFDIM;
      dst[i] = __float2bfloat16(src[(size_t)f * EMB + e]);
    }
  }
}

// ---------------- Kernel 1: patch embedding + sinusoidal PE ----------------
__global__ void patch_pe_kernel(const float* __restrict__ x,
                                const float* __restrict__ W,
                                const float* __restrict__ bias,
                                float* __restrict__ h,
                                __hip_bfloat16* __restrict__ hbf) {
  int gid = blockIdx.x * blockDim.x + threadIdx.x;
  if (gid >= TOK * EMB) return;
  int tok = gid / EMB;
  int e = gid % EMB;
  int b = tok / SEQ;
  int s = tok % SEQ;
  const float* xp = x + b * INPUT_SIZE + s * PATCH;
  float acc = bias[e];
#pragma unroll
  for (int p = 0; p < PATCH; p++) acc += xp[p] * W[p * EMB + e];
  int i = e >> 1;
  float freq = __expf(-(float)(2 * i) * (9.210340371976184f / 96.0f));
  float ang = (float)s * freq;
  acc += (e & 1) ? cosf(ang) : sinf(ang);
  h[gid] = acc;
  hbf[gid] = __float2bfloat16(acc);
}

// ---------------- Kernel 2: K/V projection GEMM (MFMA) ---------------------
// K half -> kbuf[bh][s][d]; V half -> vbufT[bh][d][t] via 8B packed stores.
__global__ __launch_bounds__(256) void kv_mfma_kernel(
    const __hip_bfloat16* __restrict__ hbf,
    const __hip_bfloat16* __restrict__ wkvT, const float* __restrict__ bk,
    const float* __restrict__ bv, __hip_bfloat16* __restrict__ kbuf,
    __hip_bfloat16* __restrict__ vbufT, int b0) {
  const int wave = threadIdx.x >> 6;
  const int lane = threadIdx.x & 63;
  const int tq = lane & 15;
  const int quad = lane >> 4;
  const int m0 = blockIdx.x * 64 + wave * 16;  // token tile row (chunk-local)
  const int n0 = blockIdx.y * 64;

  const short* ap =
      (const short*)hbf + ((size_t)b0 * SEQ + m0 + tq) * EMB + quad * 8;
  bf16x8 a0 = *(const bf16x8*)(ap);
  bf16x8 a1 = *(const bf16x8*)(ap + 32);
  bf16x8 a2 = *(const bf16x8*)(ap + 64);

  f32x4 acc[4];
  const f32x4 zero4 = {0.f, 0.f, 0.f, 0.f};
#pragma unroll
  for (int nt = 0; nt < 4; nt++) acc[nt] = zero4;
#pragma unroll
  for (int nt = 0; nt < 4; nt++) {
    const short* bp =
        (const short*)wkvT + (size_t)(n0 + nt * 16 + tq) * EMB + quad * 8;
    bf16x8 b0f = *(const bf16x8*)(bp);
    bf16x8 b1f = *(const bf16x8*)(bp + 32);
    bf16x8 b2f = *(const bf16x8*)(bp + 64);
    acc[nt] = __builtin_amdgcn_mfma_f32_16x16x32_bf16(a0, b0f, acc[nt], 0, 0, 0);
    acc[nt] = __builtin_amdgcn_mfma_f32_16x16x32_bf16(a1, b1f, acc[nt], 0, 0, 0);
    acc[nt] = __builtin_amdgcn_mfma_f32_16x16x32_bf16(a2, b2f, acc[nt], 0, 0, 0);
  }

  // rows are tokens tl = m0 + quad*4 + j (j=0..3): same batch, s consecutive
  const int tl0 = m0 + quad * 4;
  const int blb = tl0 / SEQ;
  const int ss0 = tl0 - blb * SEQ;
#pragma unroll
  for (int nt = 0; nt < 4; nt++) {
    int n = n0 + nt * 16 + tq;
    int kv = n / (NHEAD * HDIM);
    int r = n - kv * (NHEAD * HDIM);  // h*96+d
    int hh = r / HDIM;
    int d = r - hh * HDIM;
    if (kv) {
      float bias = bv[r];
      bf16x4 pack;
#pragma unroll
      for (int j = 0; j < 4; j++) pack[j] = f2bf(acc[nt][j] + bias);
      *(bf16x4*)((short*)vbufT +
                 ((size_t)(blb * NHEAD + hh) * HDIM + d) * SEQ + ss0) = pack;
    } else {
      float bias = bk[r];
#pragma unroll
      for (int j = 0; j < 4; j++) {
        kbuf[((size_t)(blb * NHEAD + hh) * SEQ + ss0 + j) * HDIM + d] =
            __float2bfloat16(acc[nt][j] + bias);
      }
    }
  }
}

// ---------------- Kernel 3: MFMA attention, K-staged + split-t PV ----------
// 1D grid of 9*NHEAD*CHUNK blocks with XCD swizzle. LDS lifetimes:
// (1) Q staging (wave-local) -> (2) K staging for score phase (cooperative,
// 2 halves) -> (3) P staging (per-wave regions, read cross-wave) ->
// (4) PV partial-O reduction buffer (fp32, 12 slots x 16 x 97).
// PV is split over t across waves: wave w covers ksteps kts[w]..kte[w] for
// ALL 64 q rows (V loads /4), then partials are summed through LDS.
#define PSTRIDE 584  // Q/P view row stride (shorts)
#define KSTR 104     // K view row stride (shorts): 208B, 16B-aligned
__global__ __launch_bounds__(256, 2) void attn_mfma_kernel(
    const __hip_bfloat16* __restrict__ hbf,
    const __hip_bfloat16* __restrict__ wqT, const float* __restrict__ bq,
    const __hip_bfloat16* __restrict__ kbuf,
    const __hip_bfloat16* __restrict__ vbufT,
    __hip_bfloat16* __restrict__ heads, int b0) {
  const int flat = blockIdx.x;
  const int xcd = flat & 7;
  const int slot = flat >> 3;
  const int g = (slot / 9) * 8 + xcd;  // 0..383 group = (bl,hh)
  const int qt = slot % 9;             // 0..8
  const int hh = g % NHEAD;
  const int bl = g / NHEAD;            // local batch 0..31
  const int wave = threadIdx.x >> 6;
  const int lane = threadIdx.x & 63;
  const int tq = lane & 15;
  const int quad = lane >> 4;

  __shared__ __align__(16) short sbuf[4 * 16 * PSTRIDE];  // 74752 B
  short* pw = sbuf + wave * 16 * PSTRIDE;  // wave's Q/P region [16][PSTRIDE]

  const size_t bh = (size_t)(bl * NHEAD + hh);
  const short* kb = (const short*)kbuf + bh * SEQ * HDIM;
  const short* vb = (const short*)vbufT + bh * HDIM * SEQ;

  // ---- (1) Q projection via MFMA: 16 q rows x 96 d ----
  const int q0 = qt * 64 + wave * 16;
  int qrow = q0 + tq;
  if (qrow > SEQ - 1) qrow = SEQ - 1;
  const short* hp =
      (const short*)hbf + ((size_t)(b0 + bl) * SEQ + qrow) * EMB + quad * 8;
  bf16x8 ha0 = *(const bf16x8*)(hp);
  bf16x8 ha1 = *(const bf16x8*)(hp + 32);
  bf16x8 ha2 = *(const bf16x8*)(hp + 64);
  const f32x4 zero4 = {0.f, 0.f, 0.f, 0.f};
  f32x4 qacc[6];
#pragma unroll
  for (int dt = 0; dt < 6; dt++) qacc[dt] = zero4;
#pragma unroll
  for (int dt = 0; dt < 6; dt++) {
    const short* wp = (const short*)wqT +
                      ((size_t)hh * HDIM + dt * 16 + tq) * EMB + quad * 8;
    bf16x8 w0 = *(const bf16x8*)(wp);
    bf16x8 w1 = *(const bf16x8*)(wp + 32);
    bf16x8 w2 = *(const bf16x8*)(wp + 64);
    qacc[dt] = __builtin_amdgcn_mfma_f32_16x16x32_bf16(ha0, w0, qacc[dt], 0, 0, 0);
    qacc[dt] = __builtin_amdgcn_mfma_f32_16x16x32_bf16(ha1, w1, qacc[dt], 0, 0, 0);
    qacc[dt] = __builtin_amdgcn_mfma_f32_16x16x32_bf16(ha2, w2, qacc[dt], 0, 0, 0);
  }
  // stage Q (C-layout) into pw cols 0..95, re-read as A-frags (wave-local)
#pragma unroll
  for (int dt = 0; dt < 6; dt++) {
    int d = dt * 16 + tq;
    float bias = bq[hh * HDIM + d];
#pragma unroll
    for (int r = 0; r < 4; r++)
      pw[(quad * 4 + r) * PSTRIDE + d] = f2bf((qacc[dt][r] + bias) * SCALE);
  }
  bf16x8 aq0 = *(const bf16x8*)&pw[tq * PSTRIDE + quad * 8];
  bf16x8 aq1 = *(const bf16x8*)&pw[tq * PSTRIDE + quad * 8 + 32];
  bf16x8 aq2 = *(const bf16x8*)&pw[tq * PSTRIDE + quad * 8 + 64];
  __syncthreads();  // all waves have Q in regs; sbuf free for K staging

  f32x4 acc[35];
#pragma unroll
  for (int tt = 0; tt < 35; tt++) acc[tt] = zero4;

  // ---- (2a) stage K rows [0,288) and compute score tiles 0..17 ----
  for (int i = threadIdx.x; i < 288 * 12; i += 256) {
    int row = i / 12, gg = i - row * 12;
    *(bf16x8*)&sbuf[row * KSTR + gg * 8] =
        *(const bf16x8*)(kb + (size_t)row * HDIM + gg * 8);
  }
  __syncthreads();
#pragma unroll
  for (int tt = 0; tt < 18; tt++) {
    const short* kp = &sbuf[(tt * 16 + tq) * KSTR + quad * 8];
    bf16x8 kb0 = *(const bf16x8*)(kp);
    bf16x8 kb1 = *(const bf16x8*)(kp + 32);
    bf16x8 kb2 = *(const bf16x8*)(kp + 64);
    acc[tt] = __builtin_amdgcn_mfma_f32_16x16x32_bf16(aq0, kb0, acc[tt], 0, 0, 0);
    acc[tt] = __builtin_amdgcn_mfma_f32_16x16x32_bf16(aq1, kb1, acc[tt], 0, 0, 0);
    acc[tt] = __builtin_amdgcn_mfma_f32_16x16x32_bf16(aq2, kb2, acc[tt], 0, 0, 0);
  }
  __syncthreads();

  // ---- (2b) stage K rows [288,560) and compute score tiles 18..34 ----
  for (int i = threadIdx.x; i < 272 * 12; i += 256) {
    int row = i / 12, gg = i - row * 12;
    *(bf16x8*)&sbuf[row * KSTR + gg * 8] =
        *(const bf16x8*)(kb + (size_t)(288 + row) * HDIM + gg * 8);
  }
  __syncthreads();
#pragma unroll
  for (int tt = 18; tt < 35; tt++) {
    const short* kp = &sbuf[(tt * 16 + tq - 288) * KSTR + quad * 8];
    bf16x8 kb0 = *(const bf16x8*)(kp);
    bf16x8 kb1 = *(const bf16x8*)(kp + 32);
    bf16x8 kb2 = *(const bf16x8*)(kp + 64);
    acc[tt] = __builtin_amdgcn_mfma_f32_16x16x32_bf16(aq0, kb0, acc[tt], 0, 0, 0);
    acc[tt] = __builtin_amdgcn_mfma_f32_16x16x32_bf16(aq1, kb1, acc[tt], 0, 0, 0);
    acc[tt] = __builtin_amdgcn_mfma_f32_16x16x32_bf16(aq2, kb2, acc[tt], 0, 0, 0);
  }

  // ---- softmax ----
  float m0 = -1e30f, m1 = -1e30f, m2 = -1e30f, m3 = -1e30f;
#pragma unroll
  for (int tt = 0; tt < 35; tt++) {
    m0 = fmaxf(m0, acc[tt][0]);
    m1 = fmaxf(m1, acc[tt][1]);
    m2 = fmaxf(m2, acc[tt][2]);
    m3 = fmaxf(m3, acc[tt][3]);
  }
#pragma unroll
  for (int mask = 1; mask < 16; mask <<= 1) {
    m0 = fmaxf(m0, __shfl_xor(m0, mask, 64));
    m1 = fmaxf(m1, __shfl_xor(m1, mask, 64));
    m2 = fmaxf(m2, __shfl_xor(m2, mask, 64));
    m3 = fmaxf(m3, __shfl_xor(m3, mask, 64));
  }
  float l0 = 0.f, l1 = 0.f, l2 = 0.f, l3 = 0.f;
#pragma unroll
  for (int tt = 0; tt < 35; tt++) {
    float p0 = __expf(acc[tt][0] - m0); acc[tt][0] = p0; l0 += p0;
    float p1 = __expf(acc[tt][1] - m1); acc[tt][1] = p1; l1 += p1;
    float p2 = __expf(acc[tt][2] - m2); acc[tt][2] = p2; l2 += p2;
    float p3 = __expf(acc[tt][3] - m3); acc[tt][3] = p3; l3 += p3;
  }
#pragma unroll
  for (int mask = 1; mask < 16; mask <<= 1) {
    l0 += __shfl_xor(l0, mask, 64);
    l1 += __shfl_xor(l1, mask, 64);
    l2 += __shfl_xor(l2, mask, 64);
    l3 += __shfl_xor(l3, mask, 64);
  }
  __syncthreads();  // all waves done reading K from sbuf

  // ---- (3) P -> pw (A-layout, unnormalized) ----
  for (int i = lane; i < 256; i += 64)
    pw[(i >> 4) * PSTRIDE + 560 + (i & 15)] = 0;  // zero t-pad cols 560..575
#pragma unroll
  for (int tt = 0; tt < 35; tt++) {
    int col = tt * 16 + tq;
    pw[(quad * 4 + 0) * PSTRIDE + col] = f2bf(acc[tt][0]);
    pw[(quad * 4 + 1) * PSTRIDE + col] = f2bf(acc[tt][1]);
    pw[(quad * 4 + 2) * PSTRIDE + col] = f2bf(acc[tt][2]);
    pw[(quad * 4 + 3) * PSTRIDE + col] = f2bf(acc[tt][3]);
  }
  __syncthreads();  // P visible to all waves

  // ---- (4) split-t PV: wave w covers ksteps kts[w]..kte[w] for all 64 q ---
  const int kts[4] = {0, 5, 10, 14};
  const int kte[4] = {5, 10, 14, 18};
  f32x4 oacc[4][6];
#pragma unroll
  for (int mt = 0; mt < 4; mt++)
#pragma unroll
    for (int dt = 0; dt < 6; dt++) oacc[mt][dt] = zero4;
  for (int kt = kts[wave]; kt < kte[wave]; kt++) {
    bf16x8 pa[4];
#pragma unroll
    for (int mt = 0; mt < 4; mt++)
      pa[mt] = *(const bf16x8*)&sbuf[(mt * 16 + tq) * PSTRIDE + kt * 32 + quad * 8];
#pragma unroll
    for (int dt = 0; dt < 6; dt++) {
      const short* vp = vb + (size_t)(dt * 16 + tq) * SEQ + kt * 32 + quad * 8;
      bf16x8 vf = *(const bf16x8*)vp;  // last ksteps read ≤32B past row end;
                                       // P pad cols are 0, alloc-safe (heads follows)
#pragma unroll
      for (int mt = 0; mt < 4; mt++)
        oacc[mt][dt] =
            __builtin_amdgcn_mfma_f32_16x16x32_bf16(pa[mt], vf, oacc[mt][dt], 0, 0, 0);
    }
  }
  __syncthreads();  // all P reads done; sbuf reusable as reduction buffer

  // write partials for the 3 q-ranges this wave does NOT own
  float* redf = (float*)sbuf;  // [12 slots][16 q][97] fp32 = 74.5 KB
#pragma unroll
  for (int mt = 0; mt < 4; mt++) {
    if (mt == wave) continue;
    int sr = (wave < mt) ? wave : wave - 1;
#pragma unroll
    for (int dt = 0; dt < 6; dt++) {
#pragma unroll
      for (int r = 0; r < 4; r++)
        redf[((mt * 3 + sr) * 16 + quad * 4 + r) * 97 + dt * 16 + tq] =
            oacc[mt][dt][r];
    }
  }
  __syncthreads();

  // own range: regs + 3 LDS partials, normalize, store
  f32x4 fin[6];
#pragma unroll
  for (int dt = 0; dt < 6; dt++) {
    fin[dt] = oacc[wave][dt];
#pragma unroll
    for (int sr = 0; sr < 3; sr++) {
#pragma unroll
      for (int r = 0; r < 4; r++)
        fin[dt][r] +=
            redf[((wave * 3 + sr) * 16 + quad * 4 + r) * 97 + dt * 16 + tq];
    }
  }
  float r0 = 1.f / l0, r1 = 1.f / l1, r2 = 1.f / l2, r3 = 1.f / l3;
  int qg = q0 + quad * 4;
  __hip_bfloat16* hpout =
      heads + ((size_t)(b0 + bl) * SEQ) * (NHEAD * HDIM) + (size_t)hh * HDIM;
#pragma unroll
  for (int dt = 0; dt < 6; dt++) {
    int d = dt * 16 + tq;
    if (qg + 0 < SEQ) hpout[(size_t)(qg + 0) * (NHEAD * HDIM) + d] = __float2bfloat16(fin[dt][0] * r0);
    if (qg + 1 < SEQ) hpout[(size_t)(qg + 1) * (NHEAD * HDIM) + d] = __float2bfloat16(fin[dt][1] * r1);
    if (qg + 2 < SEQ) hpout[(size_t)(qg + 2) * (NHEAD * HDIM) + d] = __float2bfloat16(fin[dt][2] * r2);
    if (qg + 3 < SEQ) hpout[(size_t)(qg + 3) * (NHEAD * HDIM) + d] = __float2bfloat16(fin[dt][3] * r3);
  }
}

// ---------------- Kernel 4: Wo GEMM + residual + LayerNorm (MFMA, proven) --
__global__ __launch_bounds__(256) void wo_ln_mfma_kernel(
    const __hip_bfloat16* __restrict__ heads,
    const __hip_bfloat16* __restrict__ woT, const float* __restrict__ bo,
    const float* __restrict__ gamma, const float* __restrict__ beta,
    const float* __restrict__ hres, float* __restrict__ hA,
    __hip_bfloat16* __restrict__ hbf) {
  const int wave = threadIdx.x >> 6;
  const int lane = threadIdx.x & 63;
  const int tq = lane & 15;
  const int quad = lane >> 4;
  const int m0 = blockIdx.x * 64 + wave * 16;

  const short* ap = (const short*)heads + (size_t)(m0 + tq) * (NHEAD * HDIM);
  const short* bp = (const short*)woT;

  f32x4 acc[6];
  const f32x4 zero4 = {0.f, 0.f, 0.f, 0.f};
#pragma unroll
  for (int dt = 0; dt < 6; dt++) acc[dt] = zero4;

  for (int kt = 0; kt < 36; kt++) {
    bf16x8 af = *(const bf16x8*)(ap + kt * 32 + quad * 8);
#pragma unroll
    for (int dt = 0; dt < 6; dt++) {
      bf16x8 bfr = *(const bf16x8*)(bp + (size_t)(dt * 16 + tq) * (NHEAD * HDIM) +
                                    kt * 32 + quad * 8);
      acc[dt] = __builtin_amdgcn_mfma_f32_16x16x32_bf16(af, bfr, acc[dt], 0, 0, 0);
    }
  }

  const int tok0 = m0 + quad * 4;
  float s1[4] = {0.f, 0.f, 0.f, 0.f};
  float s2[4] = {0.f, 0.f, 0.f, 0.f};
#pragma unroll
  for (int dt = 0; dt < 6; dt++) {
    int n = dt * 16 + tq;
    float bias = bo[n];
#pragma unroll
    for (int r = 0; r < 4; r++) {
      float val = acc[dt][r] + bias + hres[(size_t)(tok0 + r) * EMB + n];
      acc[dt][r] = val;
      s1[r] += val;
      s2[r] += val * val;
    }
  }
#pragma unroll
  for (int mask = 1; mask < 16; mask <<= 1) {
#pragma unroll
    for (int r = 0; r < 4; r++) {
      s1[r] += __shfl_xor(s1[r], mask, 64);
      s2[r] += __shfl_xor(s2[r], mask, 64);
    }
  }
  float mean[4], rstd[4];
#pragma unroll
  for (int r = 0; r < 4; r++) {
    mean[r] = s1[r] * (1.0f / EMB);
    float var = s2[r] * (1.0f / EMB) - mean[r] * mean[r];
    rstd[r] = rsqrtf(var + EPSV);
  }
#pragma unroll
  for (int dt = 0; dt < 6; dt++) {
    int n = dt * 16 + tq;
    float g = gamma[n], bt = beta[n];
#pragma unroll
    for (int r = 0; r < 4; r++) {
      float o = (acc[dt][r] - mean[r]) * rstd[r] * g + bt;
      hA[(size_t)(tok0 + r) * EMB + n] = o;
      hbf[(size_t)(tok0 + r) * EMB + n] = __float2bfloat16(o);
    }
  }
}

// ---------------- Kernel 5: FF1 GEMM + ReLU (MFMA) -------------------------
__global__ __launch_bounds__(256) void ff1_mfma_kernel(
    const __hip_bfloat16* __restrict__ hbf,
    const __hip_bfloat16* __restrict__ ff1WT, const float* __restrict__ b1,
    __hip_bfloat16* __restrict__ ffbf) {
  const int wave = threadIdx.x >> 6;
  const int lane = threadIdx.x & 63;
  const int tq = lane & 15;
  const int quad = lane >> 4;
  const int m0 = blockIdx.x * 64 + wave * 16;

  const short* ap = (const short*)hbf + (size_t)(m0 + tq) * EMB + quad * 8;
  bf16x8 a0 = *(const bf16x8*)(ap);
  bf16x8 a1 = *(const bf16x8*)(ap + 32);
  bf16x8 a2 = *(const bf16x8*)(ap + 64);

  f32x4 acc[16];
  const f32x4 zero4 = {0.f, 0.f, 0.f, 0.f};
#pragma unroll
  for (int nt = 0; nt < 16; nt++) acc[nt] = zero4;
#pragma unroll
  for (int nt = 0; nt < 16; nt++) {
    const short* bp =
        (const short*)ff1WT + (size_t)(nt * 16 + tq) * EMB + quad * 8;
    bf16x8 b0f = *(const bf16x8*)(bp);
    bf16x8 b1f = *(const bf16x8*)(bp + 32);
    bf16x8 b2f = *(const bf16x8*)(bp + 64);
    acc[nt] = __builtin_amdgcn_mfma_f32_16x16x32_bf16(a0, b0f, acc[nt], 0, 0, 0);
    acc[nt] = __builtin_amdgcn_mfma_f32_16x16x32_bf16(a1, b1f, acc[nt], 0, 0, 0);
    acc[nt] = __builtin_amdgcn_mfma_f32_16x16x32_bf16(a2, b2f, acc[nt], 0, 0, 0);
  }

  const int tok0 = m0 + quad * 4;
#pragma unroll
  for (int nt = 0; nt < 16; nt++) {
    int n = nt * 16 + tq;
    float bias = b1[n];
#pragma unroll
    for (int r = 0; r < 4; r++) {
      ffbf[(size_t)(tok0 + r) * FFDIM + n] =
          __float2bfloat16(fmaxf(acc[nt][r] + bias, 0.f));
    }
  }
}

// ---------------- Kernel 6: FF2 GEMM + residual + LN (MFMA) ----------------
__global__ __launch_bounds__(256) void ff2_ln_mfma_kernel(
    const __hip_bfloat16* __restrict__ ffbf,
    const __hip_bfloat16* __restrict__ ff2WT, const float* __restrict__ b2,
    const float* __restrict__ gamma, const float* __restrict__ beta,
    const float* __restrict__ hres, float* __restrict__ hout,
    __hip_bfloat16* __restrict__ hbf_out) {
  const int wave = threadIdx.x >> 6;
  const int lane = threadIdx.x & 63;
  const int tq = lane & 15;
  const int quad = lane >> 4;
  const int m0 = blockIdx.x * 64 + wave * 16;

  const short* ap = (const short*)ffbf + (size_t)(m0 + tq) * FFDIM;
  const short* bp = (const short*)ff2WT;

  f32x4 acc[6];
  const f32x4 zero4 = {0.f, 0.f, 0.f, 0.f};
#pragma unroll
  for (int dt = 0; dt < 6; dt++) acc[dt] = zero4;

#pragma unroll
  for (int kt = 0; kt < 8; kt++) {
    bf16x8 af = *(const bf16x8*)(ap + kt * 32 + quad * 8);
#pragma unroll
    for (int dt = 0; dt < 6; dt++) {
      bf16x8 bfr = *(const bf16x8*)(bp + (size_t)(dt * 16 + tq) * FFDIM +
                                    kt * 32 + quad * 8);
      acc[dt] = __builtin_amdgcn_mfma_f32_16x16x32_bf16(af, bfr, acc[dt], 0, 0, 0);
    }
  }

  const int tok0 = m0 + quad * 4;
  float s1[4] = {0.f, 0.f, 0.f, 0.f};
  float s2[4] = {0.f, 0.f, 0.f, 0.f};
#pragma unroll
  for (int dt = 0; dt < 6; dt++) {
    int n = dt * 16 + tq;
    float bias = b2[n];
#pragma unroll
    for (int r = 0; r < 4; r++) {
      float val = acc[dt][r] + bias + hres[(size_t)(tok0 + r) * EMB + n];
      acc[dt][r] = val;
      s1[r] += val;
      s2[r] += val * val;
    }
  }
#pragma unroll
  for (int mask = 1; mask < 16; mask <<= 1) {
#pragma unroll
    for (int r = 0; r < 4; r++) {
      s1[r] += __shfl_xor(s1[r], mask, 64);
      s2[r] += __shfl_xor(s2[r], mask, 64);
    }
  }
  float mean[4], rstd[4];
#pragma unroll
  for (int r = 0; r < 4; r++) {
    mean[r] = s1[r] * (1.0f / EMB);
    float var = s2[r] * (1.0f / EMB) - mean[r] * mean[r];
    rstd[r] = rsqrtf(var + EPSV);
  }
#pragma unroll
  for (int dt = 0; dt < 6; dt++) {
    int n = dt * 16 + tq;
    float g = gamma[n], bt = beta[n];
#pragma unroll
    for (int r = 0; r < 4; r++) {
      float o = (acc[dt][r] - mean[r]) * rstd[r] * g + bt;
      hout[(size_t)(tok0 + r) * EMB + n] = o;
      hbf_out[(size_t)(tok0 + r) * EMB + n] = __float2bfloat16(o);
    }
  }
}

// ---------------- launch ----------------------------------------------------
extern "C" void kernel_launch(void* const* d_in, const int* in_sizes, int n_in,
                              void* d_out, int out_size, void* d_ws,
                              size_t ws_size, hipStream_t stream) {
  const float* x = (const float*)d_in[0];
  const float* patch_W = (const float*)d_in[1];
  const float* patch_b = (const float*)d_in[2];
  const float* Wq = (const float*)d_in[3];
  const float* bq = (const float*)d_in[4];
  const float* Wk = (const float*)d_in[5];
  const float* bk = (const float*)d_in[6];
  const float* Wv = (const float*)d_in[7];
  const float* bv = (const float*)d_in[8];
  const float* Wo = (const float*)d_in[9];
  const float* bo = (const float*)d_in[10];
  const float* ff1_W = (const float*)d_in[11];
  const float* ff1_b = (const float*)d_in[12];
  const float* ff2_W = (const float*)d_in[13];
  const float* ff2_b = (const float*)d_in[14];
  const float* n1_g = (const float*)d_in[15];
  const float* n1_b = (const float*)d_in[16];
  const float* n2_g = (const float*)d_in[17];
  const float* n2_b = (const float*)d_in[18];

  // workspace layout (~202 MB)
  const size_t h_bytes = (size_t)TOK * EMB * sizeof(float);          // 13.76 MB
  const size_t hbf_bytes = (size_t)TOK * EMB * 2;                    // 6.88 MB
  const size_t kv_bytes = (size_t)CHUNK * NHEAD * SEQ * HDIM * 2;    // 41.29 MB
  const size_t heads_bytes = (size_t)TOK * NHEAD * HDIM * 2;         // 82.58 MB
  const size_t wqT_bytes = (size_t)NLAYER * NHEAD * HDIM * EMB * 2;  // 0.44 MB
  const size_t wkvT_bytes = 2 * wqT_bytes;                           // 0.88 MB
  const size_t woT_bytes = (size_t)NLAYER * EMB * NHEAD * HDIM * 2;  // 0.44 MB
  const size_t ffw_bytes = (size_t)NLAYER * FFDIM * EMB * 2;         // 0.10 MB
  char* ws = (char*)d_ws;
  size_t off = 0;
  float* h = (float*)(ws + off); off += h_bytes;
  float* hA = (float*)(ws + off); off += h_bytes;
  __hip_bfloat16* hbf = (__hip_bfloat16*)(ws + off); off += hbf_bytes;
  __hip_bfloat16* kbuf = (__hip_bfloat16*)(ws + off); off += kv_bytes;
  __hip_bfloat16* vbufT = (__hip_bfloat16*)(ws + off); off += kv_bytes;
  __hip_bfloat16* heads = (__hip_bfloat16*)(ws + off); off += heads_bytes;
  __hip_bfloat16* wqT = (__hip_bfloat16*)(ws + off); off += wqT_bytes;
  __hip_bfloat16* wkvT = (__hip_bfloat16*)(ws + off); off += wkvT_bytes;
  __hip_bfloat16* woT = (__hip_bfloat16*)(ws + off); off += woT_bytes;
  __hip_bfloat16* ff1WT = (__hip_bfloat16*)(ws + off); off += ffw_bytes;
  __hip_bfloat16* ff2WT = (__hip_bfloat16*)(ws + off); off += ffw_bytes;
  __hip_bfloat16* ffbf = (__hip_bfloat16*)kbuf;  // alias: free after attention

  wprep_kernel<<<dim3(NHEAD, 3, NLAYER), 256, 0, stream>>>(Wq, Wk, Wv, wqT, wkvT);
  woprep_kernel<<<NLAYER, 256, 0, stream>>>(Wo, woT);
  ffprep_kernel<<<dim3(2, NLAYER), 256, 0, stream>>>(ff1_W, ff2_W, ff1WT, ff2WT);
  patch_pe_kernel<<<(TOK * EMB + 255) / 256, 256, 0, stream>>>(x, patch_W,
                                                               patch_b, h, hbf);

  for (int l = 0; l < NLAYER; l++) {
    const __hip_bfloat16* wqT_l = wqT + (size_t)l * NHEAD * HDIM * EMB;
    const __hip_bfloat16* wkvT_l = wkvT + (size_t)l * 2 * NHEAD * HDIM * EMB;
    const __hip_bfloat16* woT_l = woT + (size_t)l * EMB * NHEAD * HDIM;
    const __hip_bfloat16* ff1WT_l = ff1WT + (size_t)l * FFDIM * EMB;
    const __hip_bfloat16* ff2WT_l = ff2WT + (size_t)l * EMB * FFDIM;
    const float* bq_l = bq + (size_t)l * NHEAD * HDIM;
    const float* bk_l = bk + (size_t)l * NHEAD * HDIM;
    const float* bv_l = bv + (size_t)l * NHEAD * HDIM;
    const float* bo_l = bo + (size_t)l * EMB;

    for (int c = 0; c < BATCH / CHUNK; c++) {
      int b0 = c * CHUNK;
      kv_mfma_kernel<<<dim3(CHUNK * SEQ / 64, 2 * NHEAD * HDIM / 64), 256, 0,
                       stream>>>(hbf, wkvT_l, bk_l, bv_l, kbuf, vbufT, b0);
      attn_mfma_kernel<<<9 * NHEAD * CHUNK, 256, 0, stream>>>(
          hbf, wqT_l, bq_l, kbuf, vbufT, heads, b0);
    }
    // LN1: reads residual h, writes hA (fp32) + hbf (bf16)
    wo_ln_mfma_kernel<<<TOK / 64, 256, 0, stream>>>(
        heads, woT_l, bo_l, n1_g + l * EMB, n1_b + l * EMB, h, hA, hbf);
    // FF path (MFMA): ff1 reads hbf -> ffbf; ff2 reads ffbf + hA residual
    ff1_mfma_kernel<<<TOK / 64, 256, 0, stream>>>(hbf, ff1WT_l,
                                                  ff1_b + l * FFDIM, ffbf);
    float* dst = (l == NLAYER - 1) ? (float*)d_out : h;
    ff2_ln_mfma_kernel<<<TOK / 64, 256, 0, stream>>>(
        ffbf, ff2WT_l, ff2_b + l * EMB, n2_g + l * EMB, n2_b + l * EMB, hA,
        dst, hbf);
  }
}

// Round 11
// 1588.438 us; speedup vs baseline: 1.0166x; 1.0166x over previous
//
#include <hip/hip_runtime.h>
#include <hip/hip_bf16.h>
#include <math.h>

#define BATCH 64
#define CHUNK 32           // batch chunk for k/v scratch
#define INPUT_SIZE 10080
#define PATCH 18
#define SEQ 560            // S
#define EMB 96             // E
#define NHEAD 12           // H
#define HDIM 96            // D
#define FFDIM 256          // F
#define NLAYER 2
#define TOK (BATCH * SEQ)  // 35840 tokens
#define EPSV 1e-5f
#define SCALE 0.10206207261596577f  // 1/sqrt(96)

typedef __attribute__((ext_vector_type(8))) short bf16x8;  // 8 bf16 (4 VGPRs)
typedef __attribute__((ext_vector_type(4))) short bf16x4;  // 4 bf16 (8B store)
typedef __attribute__((ext_vector_type(4))) float f32x4;   // 4 fp32 acc

static __device__ __forceinline__ short f2bf(float x) {
  union { __hip_bfloat16 b; short s; } u;
  u.b = __float2bfloat16(x);
  return u.s;
}

// ---------------- Kernel 0a: QKV weight transpose prep ---------------------
// wqT:  [L][H][D][E] bf16 ; wkvT: [L][2*H*D][E] bf16 (k rows then v rows)
__global__ __launch_bounds__(256) void wprep_kernel(
    const float* __restrict__ Wq, const float* __restrict__ Wk,
    const float* __restrict__ Wv, __hip_bfloat16* __restrict__ wqT,
    __hip_bfloat16* __restrict__ wkvT) {
  int hh = blockIdx.x, mat = blockIdx.y, l = blockIdx.z;
  const float* src =
      (mat == 0 ? Wq : (mat == 1 ? Wk : Wv)) + ((size_t)l * NHEAD + hh) * EMB * HDIM;
  __shared__ float t[HDIM * 97];
  for (int i = threadIdx.x; i < EMB * HDIM; i += 256) {
    int e = i / HDIM, d = i % HDIM;
    t[d * 97 + e] = src[i];
  }
  __syncthreads();
  __hip_bfloat16* dst;
  if (mat == 0)
    dst = wqT + ((size_t)l * NHEAD + hh) * HDIM * EMB;
  else
    dst = wkvT + ((size_t)l * 2 * NHEAD * HDIM + (mat - 1) * NHEAD * HDIM +
                  hh * HDIM) * EMB;
  for (int j = threadIdx.x; j < HDIM * EMB; j += 256) {
    int d = j / EMB, e = j % EMB;
    dst[j] = __float2bfloat16(t[d * 97 + e]);
  }
}

// ---------------- Kernel 0b: Wo transpose prep -----------------------------
// woT: [L][E=96][HD=1152]   (Wo is [L][1152][96])
__global__ __launch_bounds__(256) void woprep_kernel(
    const float* __restrict__ Wo, __hip_bfloat16* __restrict__ woT) {
  int l = blockIdx.x;
  const float* src = Wo + (size_t)l * NHEAD * HDIM * EMB;
  __hip_bfloat16* dst = woT + (size_t)l * EMB * NHEAD * HDIM;
  for (int i = threadIdx.x; i < EMB * NHEAD * HDIM; i += 256) {
    int e = i / (NHEAD * HDIM), j = i % (NHEAD * HDIM);
    dst[i] = __float2bfloat16(src[(size_t)j * EMB + e]);
  }
}

// ---------------- Kernel 0c: FF weight transpose prep ----------------------
// ff1WT: [L][F=256][E=96]  (ff1_W is [L][96][256]) ; ff2WT: [L][E=96][F=256]
__global__ __launch_bounds__(256) void ffprep_kernel(
    const float* __restrict__ ff1_W, const float* __restrict__ ff2_W,
    __hip_bfloat16* __restrict__ ff1WT, __hip_bfloat16* __restrict__ ff2WT) {
  int mat = blockIdx.x, l = blockIdx.y;
  if (mat == 0) {
    const float* src = ff1_W + (size_t)l * EMB * FFDIM;
    __hip_bfloat16* dst = ff1WT + (size_t)l * FFDIM * EMB;
    for (int i = threadIdx.x; i < FFDIM * EMB; i += 256) {
      int f = i / EMB, e = i % EMB;
      dst[i] = __float2bfloat16(src[(size_t)e * FFDIM + f]);
    }
  } else {
    const float* src = ff2_W + (size_t)l * FFDIM * EMB;
    __hip_bfloat16* dst = ff2WT + (size_t)l * EMB * FFDIM;
    for (int i = threadIdx.x; i < EMB * FFDIM; i += 256) {
      int e = i / FFDIM, f = i % FFDIM;
      dst[i] = __float2bfloat16(src[(size_t)f * EMB + e]);
    }
  }
}

// ---------------- Kernel 1: patch embedding + sinusoidal PE ----------------
__global__ void patch_pe_kernel(const float* __restrict__ x,
                                const float* __restrict__ W,
                                const float* __restrict__ bias,
                                float* __restrict__ h,
                                __hip_bfloat16* __restrict__ hbf) {
  int gid = blockIdx.x * blockDim.x + threadIdx.x;
  if (gid >= TOK * EMB) return;
  int tok = gid / EMB;
  int e = gid % EMB;
  int b = tok / SEQ;
  int s = tok % SEQ;
  const float* xp = x + b * INPUT_SIZE + s * PATCH;
  float acc = bias[e];
#pragma unroll
  for (int p = 0; p < PATCH; p++) acc += xp[p] * W[p * EMB + e];
  int i = e >> 1;
  float freq = __expf(-(float)(2 * i) * (9.210340371976184f / 96.0f));
  float ang = (float)s * freq;
  acc += (e & 1) ? cosf(ang) : sinf(ang);
  h[gid] = acc;
  hbf[gid] = __float2bfloat16(acc);
}

// ---------------- Kernel 2: K/V projection GEMM (MFMA) ---------------------
// K half -> kbuf[bh][s][d]; V half -> vbufT[bh][d][t] via 8B packed stores.
__global__ __launch_bounds__(256) void kv_mfma_kernel(
    const __hip_bfloat16* __restrict__ hbf,
    const __hip_bfloat16* __restrict__ wkvT, const float* __restrict__ bk,
    const float* __restrict__ bv, __hip_bfloat16* __restrict__ kbuf,
    __hip_bfloat16* __restrict__ vbufT, int b0) {
  const int wave = threadIdx.x >> 6;
  const int lane = threadIdx.x & 63;
  const int tq = lane & 15;
  const int quad = lane >> 4;
  const int m0 = blockIdx.x * 64 + wave * 16;  // token tile row (chunk-local)
  const int n0 = blockIdx.y * 64;

  const short* ap =
      (const short*)hbf + ((size_t)b0 * SEQ + m0 + tq) * EMB + quad * 8;
  bf16x8 a0 = *(const bf16x8*)(ap);
  bf16x8 a1 = *(const bf16x8*)(ap + 32);
  bf16x8 a2 = *(const bf16x8*)(ap + 64);

  f32x4 acc[4];
  const f32x4 zero4 = {0.f, 0.f, 0.f, 0.f};
#pragma unroll
  for (int nt = 0; nt < 4; nt++) acc[nt] = zero4;
#pragma unroll
  for (int nt = 0; nt < 4; nt++) {
    const short* bp =
        (const short*)wkvT + (size_t)(n0 + nt * 16 + tq) * EMB + quad * 8;
    bf16x8 b0f = *(const bf16x8*)(bp);
    bf16x8 b1f = *(const bf16x8*)(bp + 32);
    bf16x8 b2f = *(const bf16x8*)(bp + 64);
    acc[nt] = __builtin_amdgcn_mfma_f32_16x16x32_bf16(a0, b0f, acc[nt], 0, 0, 0);
    acc[nt] = __builtin_amdgcn_mfma_f32_16x16x32_bf16(a1, b1f, acc[nt], 0, 0, 0);
    acc[nt] = __builtin_amdgcn_mfma_f32_16x16x32_bf16(a2, b2f, acc[nt], 0, 0, 0);
  }

  // rows are tokens tl = m0 + quad*4 + j (j=0..3): same batch, s consecutive
  const int tl0 = m0 + quad * 4;
  const int blb = tl0 / SEQ;
  const int ss0 = tl0 - blb * SEQ;
#pragma unroll
  for (int nt = 0; nt < 4; nt++) {
    int n = n0 + nt * 16 + tq;
    int kv = n / (NHEAD * HDIM);
    int r = n - kv * (NHEAD * HDIM);  // h*96+d
    int hh = r / HDIM;
    int d = r - hh * HDIM;
    if (kv) {
      float bias = bv[r];
      bf16x4 pack;
#pragma unroll
      for (int j = 0; j < 4; j++) pack[j] = f2bf(acc[nt][j] + bias);
      *(bf16x4*)((short*)vbufT +
                 ((size_t)(blb * NHEAD + hh) * HDIM + d) * SEQ + ss0) = pack;
    } else {
      float bias = bk[r];
#pragma unroll
      for (int j = 0; j < 4; j++) {
        kbuf[((size_t)(blb * NHEAD + hh) * SEQ + ss0 + j) * HDIM + d] =
            __float2bfloat16(acc[nt][j] + bias);
      }
    }
  }
}

// ---------------- Kernel 3: MFMA attention, K-staged + 2-way split-t PV ----
// 1D grid of 9*NHEAD*CHUNK blocks with XCD swizzle. LDS lifetimes:
// (1) Q staging (wave-local) -> (2) K staging (cooperative, 2 halves) ->
// (3) P staging (per-wave regions, read within wave-pair) -> (4) reduction
// buffer (fp32, 4 slots x 16 x 97 = 24.8 KB).
// PV split: pair p = waves {2p,2p+1} covers q-rows [32p,32p+32); wave half
// h covers ksteps [9h,9h+9). V loads per wave halved; oacc[2][6]=48 regs
// (round-10's oacc[4][6]=96 spilled to scratch -> 702 MB writes).
#define PSTRIDE 584  // Q/P view row stride (shorts)
#define KSTR 104     // K view row stride (shorts): 208B, 16B-aligned
__global__ __launch_bounds__(256, 2) void attn_mfma_kernel(
    const __hip_bfloat16* __restrict__ hbf,
    const __hip_bfloat16* __restrict__ wqT, const float* __restrict__ bq,
    const __hip_bfloat16* __restrict__ kbuf,
    const __hip_bfloat16* __restrict__ vbufT,
    __hip_bfloat16* __restrict__ heads, int b0) {
  const int flat = blockIdx.x;
  const int xcd = flat & 7;
  const int slot = flat >> 3;
  const int g = (slot / 9) * 8 + xcd;  // 0..383 group = (bl,hh)
  const int qt = slot % 9;             // 0..8
  const int hh = g % NHEAD;
  const int bl = g / NHEAD;            // local batch 0..31
  const int wave = threadIdx.x >> 6;
  const int lane = threadIdx.x & 63;
  const int tq = lane & 15;
  const int quad = lane >> 4;

  __shared__ __align__(16) short sbuf[4 * 16 * PSTRIDE];  // 74752 B
  short* pw = sbuf + wave * 16 * PSTRIDE;  // wave's Q/P region [16][PSTRIDE]

  const size_t bh = (size_t)(bl * NHEAD + hh);
  const short* kb = (const short*)kbuf + bh * SEQ * HDIM;
  const short* vb = (const short*)vbufT + bh * HDIM * SEQ;

  // ---- (1) Q projection via MFMA: 16 q rows x 96 d ----
  const int q0 = qt * 64 + wave * 16;
  int qrow = q0 + tq;
  if (qrow > SEQ - 1) qrow = SEQ - 1;
  const short* hp =
      (const short*)hbf + ((size_t)(b0 + bl) * SEQ + qrow) * EMB + quad * 8;
  bf16x8 ha0 = *(const bf16x8*)(hp);
  bf16x8 ha1 = *(const bf16x8*)(hp + 32);
  bf16x8 ha2 = *(const bf16x8*)(hp + 64);
  const f32x4 zero4 = {0.f, 0.f, 0.f, 0.f};
  f32x4 qacc[6];
#pragma unroll
  for (int dt = 0; dt < 6; dt++) qacc[dt] = zero4;
#pragma unroll
  for (int dt = 0; dt < 6; dt++) {
    const short* wp = (const short*)wqT +
                      ((size_t)hh * HDIM + dt * 16 + tq) * EMB + quad * 8;
    bf16x8 w0 = *(const bf16x8*)(wp);
    bf16x8 w1 = *(const bf16x8*)(wp + 32);
    bf16x8 w2 = *(const bf16x8*)(wp + 64);
    qacc[dt] = __builtin_amdgcn_mfma_f32_16x16x32_bf16(ha0, w0, qacc[dt], 0, 0, 0);
    qacc[dt] = __builtin_amdgcn_mfma_f32_16x16x32_bf16(ha1, w1, qacc[dt], 0, 0, 0);
    qacc[dt] = __builtin_amdgcn_mfma_f32_16x16x32_bf16(ha2, w2, qacc[dt], 0, 0, 0);
  }
  // stage Q (C-layout) into pw cols 0..95, re-read as A-frags (wave-local)
#pragma unroll
  for (int dt = 0; dt < 6; dt++) {
    int d = dt * 16 + tq;
    float bias = bq[hh * HDIM + d];
#pragma unroll
    for (int r = 0; r < 4; r++)
      pw[(quad * 4 + r) * PSTRIDE + d] = f2bf((qacc[dt][r] + bias) * SCALE);
  }
  bf16x8 aq0 = *(const bf16x8*)&pw[tq * PSTRIDE + quad * 8];
  bf16x8 aq1 = *(const bf16x8*)&pw[tq * PSTRIDE + quad * 8 + 32];
  bf16x8 aq2 = *(const bf16x8*)&pw[tq * PSTRIDE + quad * 8 + 64];
  __syncthreads();  // all waves have Q in regs; sbuf free for K staging

  f32x4 acc[35];
#pragma unroll
  for (int tt = 0; tt < 35; tt++) acc[tt] = zero4;

  // ---- (2a) stage K rows [0,288) and compute score tiles 0..17 ----
  for (int i = threadIdx.x; i < 288 * 12; i += 256) {
    int row = i / 12, gg = i - row * 12;
    *(bf16x8*)&sbuf[row * KSTR + gg * 8] =
        *(const bf16x8*)(kb + (size_t)row * HDIM + gg * 8);
  }
  __syncthreads();
#pragma unroll
  for (int tt = 0; tt < 18; tt++) {
    const short* kp = &sbuf[(tt * 16 + tq) * KSTR + quad * 8];
    bf16x8 kb0 = *(const bf16x8*)(kp);
    bf16x8 kb1 = *(const bf16x8*)(kp + 32);
    bf16x8 kb2 = *(const bf16x8*)(kp + 64);
    acc[tt] = __builtin_amdgcn_mfma_f32_16x16x32_bf16(aq0, kb0, acc[tt], 0, 0, 0);
    acc[tt] = __builtin_amdgcn_mfma_f32_16x16x32_bf16(aq1, kb1, acc[tt], 0, 0, 0);
    acc[tt] = __builtin_amdgcn_mfma_f32_16x16x32_bf16(aq2, kb2, acc[tt], 0, 0, 0);
  }
  __syncthreads();

  // ---- (2b) stage K rows [288,560) and compute score tiles 18..34 ----
  for (int i = threadIdx.x; i < 272 * 12; i += 256) {
    int row = i / 12, gg = i - row * 12;
    *(bf16x8*)&sbuf[row * KSTR + gg * 8] =
        *(const bf16x8*)(kb + (size_t)(288 + row) * HDIM + gg * 8);
  }
  __syncthreads();
#pragma unroll
  for (int tt = 18; tt < 35; tt++) {
    const short* kp = &sbuf[(tt * 16 + tq - 288) * KSTR + quad * 8];
    bf16x8 kb0 = *(const bf16x8*)(kp);
    bf16x8 kb1 = *(const bf16x8*)(kp + 32);
    bf16x8 kb2 = *(const bf16x8*)(kp + 64);
    acc[tt] = __builtin_amdgcn_mfma_f32_16x16x32_bf16(aq0, kb0, acc[tt], 0, 0, 0);
    acc[tt] = __builtin_amdgcn_mfma_f32_16x16x32_bf16(aq1, kb1, acc[tt], 0, 0, 0);
    acc[tt] = __builtin_amdgcn_mfma_f32_16x16x32_bf16(aq2, kb2, acc[tt], 0, 0, 0);
  }

  // ---- softmax ----
  float m0 = -1e30f, m1 = -1e30f, m2 = -1e30f, m3 = -1e30f;
#pragma unroll
  for (int tt = 0; tt < 35; tt++) {
    m0 = fmaxf(m0, acc[tt][0]);
    m1 = fmaxf(m1, acc[tt][1]);
    m2 = fmaxf(m2, acc[tt][2]);
    m3 = fmaxf(m3, acc[tt][3]);
  }
#pragma unroll
  for (int mask = 1; mask < 16; mask <<= 1) {
    m0 = fmaxf(m0, __shfl_xor(m0, mask, 64));
    m1 = fmaxf(m1, __shfl_xor(m1, mask, 64));
    m2 = fmaxf(m2, __shfl_xor(m2, mask, 64));
    m3 = fmaxf(m3, __shfl_xor(m3, mask, 64));
  }
  float l0 = 0.f, l1 = 0.f, l2 = 0.f, l3 = 0.f;
#pragma unroll
  for (int tt = 0; tt < 35; tt++) {
    float p0 = __expf(acc[tt][0] - m0); acc[tt][0] = p0; l0 += p0;
    float p1 = __expf(acc[tt][1] - m1); acc[tt][1] = p1; l1 += p1;
    float p2 = __expf(acc[tt][2] - m2); acc[tt][2] = p2; l2 += p2;
    float p3 = __expf(acc[tt][3] - m3); acc[tt][3] = p3; l3 += p3;
  }
#pragma unroll
  for (int mask = 1; mask < 16; mask <<= 1) {
    l0 += __shfl_xor(l0, mask, 64);
    l1 += __shfl_xor(l1, mask, 64);
    l2 += __shfl_xor(l2, mask, 64);
    l3 += __shfl_xor(l3, mask, 64);
  }
  __syncthreads();  // all waves done reading K from sbuf

  // ---- (3) P -> pw (A-layout, unnormalized) ----
  for (int i = lane; i < 256; i += 64)
    pw[(i >> 4) * PSTRIDE + 560 + (i & 15)] = 0;  // zero t-pad cols 560..575
#pragma unroll
  for (int tt = 0; tt < 35; tt++) {
    int col = tt * 16 + tq;
    pw[(quad * 4 + 0) * PSTRIDE + col] = f2bf(acc[tt][0]);
    pw[(quad * 4 + 1) * PSTRIDE + col] = f2bf(acc[tt][1]);
    pw[(quad * 4 + 2) * PSTRIDE + col] = f2bf(acc[tt][2]);
    pw[(quad * 4 + 3) * PSTRIDE + col] = f2bf(acc[tt][3]);
  }
  __syncthreads();  // P visible within wave-pair

  // ---- (4) 2-way split-t PV ----
  const int pair = wave >> 1;   // 0: q-rows 0..31; 1: q-rows 32..63
  const int half = wave & 1;    // 0: ksteps 0..8;  1: ksteps 9..17
  const int mtb = pair * 2;
  f32x4 oacc[2][6];
#pragma unroll
  for (int mt = 0; mt < 2; mt++)
#pragma unroll
    for (int dt = 0; dt < 6; dt++) oacc[mt][dt] = zero4;
#pragma unroll
  for (int i = 0; i < 9; i++) {
    int kt = half * 9 + i;
    bf16x8 pa0 =
        *(const bf16x8*)&sbuf[(mtb * 16 + tq) * PSTRIDE + kt * 32 + quad * 8];
    bf16x8 pa1 = *(const bf16x8*)&sbuf[((mtb + 1) * 16 + tq) * PSTRIDE +
                                       kt * 32 + quad * 8];
#pragma unroll
    for (int dt = 0; dt < 6; dt++) {
      const short* vp = vb + (size_t)(dt * 16 + tq) * SEQ + kt * 32 + quad * 8;
      bf16x8 vf = *(const bf16x8*)vp;  // last kstep reads ≤32B past row end;
                                       // P pad cols are 0, alloc-safe
      oacc[0][dt] = __builtin_amdgcn_mfma_f32_16x16x32_bf16(pa0, vf, oacc[0][dt], 0, 0, 0);
      oacc[1][dt] = __builtin_amdgcn_mfma_f32_16x16x32_bf16(pa1, vf, oacc[1][dt], 0, 0, 0);
    }
  }
  __syncthreads();  // all P reads done; sbuf reusable as reduction buffer

  // each wave writes its partial for the range owned by its pair-buddy
  float* redf = (float*)sbuf;  // [4 slots][16 q][97] fp32 = 24.8 KB
  {
    const int buddy = wave ^ 1;
    const int mloc = buddy - mtb;  // 0 or 1
#pragma unroll
    for (int dt = 0; dt < 6; dt++) {
#pragma unroll
      for (int r = 0; r < 4; r++)
        redf[(buddy * 16 + quad * 4 + r) * 97 + dt * 16 + tq] =
            oacc[mloc][dt][r];
    }
  }
  __syncthreads();

  // owner: own-range partial (regs) + buddy's partial (LDS), normalize, store
  const int mown = wave - mtb;  // 0 or 1
  f32x4 fin[6];
#pragma unroll
  for (int dt = 0; dt < 6; dt++) {
    fin[dt] = oacc[mown][dt];
#pragma unroll
    for (int r = 0; r < 4; r++)
      fin[dt][r] += redf[(wave * 16 + quad * 4 + r) * 97 + dt * 16 + tq];
  }
  float r0 = 1.f / l0, r1 = 1.f / l1, r2 = 1.f / l2, r3 = 1.f / l3;
  int qg = q0 + quad * 4;
  __hip_bfloat16* hpout =
      heads + ((size_t)(b0 + bl) * SEQ) * (NHEAD * HDIM) + (size_t)hh * HDIM;
#pragma unroll
  for (int dt = 0; dt < 6; dt++) {
    int d = dt * 16 + tq;
    if (qg + 0 < SEQ) hpout[(size_t)(qg + 0) * (NHEAD * HDIM) + d] = __float2bfloat16(fin[dt][0] * r0);
    if (qg + 1 < SEQ) hpout[(size_t)(qg + 1) * (NHEAD * HDIM) + d] = __float2bfloat16(fin[dt][1] * r1);
    if (qg + 2 < SEQ) hpout[(size_t)(qg + 2) * (NHEAD * HDIM) + d] = __float2bfloat16(fin[dt][2] * r2);
    if (qg + 3 < SEQ) hpout[(size_t)(qg + 3) * (NHEAD * HDIM) + d] = __float2bfloat16(fin[dt][3] * r3);
  }
}

// ---------------- Kernel 4: Wo GEMM + residual + LayerNorm (MFMA, proven) --
__global__ __launch_bounds__(256) void wo_ln_mfma_kernel(
    const __hip_bfloat16* __restrict__ heads,
    const __hip_bfloat16* __restrict__ woT, const float* __restrict__ bo,
    const float* __restrict__ gamma, const float* __restrict__ beta,
    const float* __restrict__ hres, float* __restrict__ hA,
    __hip_bfloat16* __restrict__ hbf) {
  const int wave = threadIdx.x >> 6;
  const int lane = threadIdx.x & 63;
  const int tq = lane & 15;
  const int quad = lane >> 4;
  const int m0 = blockIdx.x * 64 + wave * 16;

  const short* ap = (const short*)heads + (size_t)(m0 + tq) * (NHEAD * HDIM);
  const short* bp = (const short*)woT;

  f32x4 acc[6];
  const f32x4 zero4 = {0.f, 0.f, 0.f, 0.f};
#pragma unroll
  for (int dt = 0; dt < 6; dt++) acc[dt] = zero4;

  for (int kt = 0; kt < 36; kt++) {
    bf16x8 af = *(const bf16x8*)(ap + kt * 32 + quad * 8);
#pragma unroll
    for (int dt = 0; dt < 6; dt++) {
      bf16x8 bfr = *(const bf16x8*)(bp + (size_t)(dt * 16 + tq) * (NHEAD * HDIM) +
                                    kt * 32 + quad * 8);
      acc[dt] = __builtin_amdgcn_mfma_f32_16x16x32_bf16(af, bfr, acc[dt], 0, 0, 0);
    }
  }

  const int tok0 = m0 + quad * 4;
  float s1[4] = {0.f, 0.f, 0.f, 0.f};
  float s2[4] = {0.f, 0.f, 0.f, 0.f};
#pragma unroll
  for (int dt = 0; dt < 6; dt++) {
    int n = dt * 16 + tq;
    float bias = bo[n];
#pragma unroll
    for (int r = 0; r < 4; r++) {
      float val = acc[dt][r] + bias + hres[(size_t)(tok0 + r) * EMB + n];
      acc[dt][r] = val;
      s1[r] += val;
      s2[r] += val * val;
    }
  }
#pragma unroll
  for (int mask = 1; mask < 16; mask <<= 1) {
#pragma unroll
    for (int r = 0; r < 4; r++) {
      s1[r] += __shfl_xor(s1[r], mask, 64);
      s2[r] += __shfl_xor(s2[r], mask, 64);
    }
  }
  float mean[4], rstd[4];
#pragma unroll
  for (int r = 0; r < 4; r++) {
    mean[r] = s1[r] * (1.0f / EMB);
    float var = s2[r] * (1.0f / EMB) - mean[r] * mean[r];
    rstd[r] = rsqrtf(var + EPSV);
  }
#pragma unroll
  for (int dt = 0; dt < 6; dt++) {
    int n = dt * 16 + tq;
    float g = gamma[n], bt = beta[n];
#pragma unroll
    for (int r = 0; r < 4; r++) {
      float o = (acc[dt][r] - mean[r]) * rstd[r] * g + bt;
      hA[(size_t)(tok0 + r) * EMB + n] = o;
      hbf[(size_t)(tok0 + r) * EMB + n] = __float2bfloat16(o);
    }
  }
}

// ---------------- Kernel 5: FF1 GEMM + ReLU (MFMA) -------------------------
__global__ __launch_bounds__(256) void ff1_mfma_kernel(
    const __hip_bfloat16* __restrict__ hbf,
    const __hip_bfloat16* __restrict__ ff1WT, const float* __restrict__ b1,
    __hip_bfloat16* __restrict__ ffbf) {
  const int wave = threadIdx.x >> 6;
  const int lane = threadIdx.x & 63;
  const int tq = lane & 15;
  const int quad = lane >> 4;
  const int m0 = blockIdx.x * 64 + wave * 16;

  const short* ap = (const short*)hbf + (size_t)(m0 + tq) * EMB + quad * 8;
  bf16x8 a0 = *(const bf16x8*)(ap);
  bf16x8 a1 = *(const bf16x8*)(ap + 32);
  bf16x8 a2 = *(const bf16x8*)(ap + 64);

  f32x4 acc[16];
  const f32x4 zero4 = {0.f, 0.f, 0.f, 0.f};
#pragma unroll
  for (int nt = 0; nt < 16; nt++) acc[nt] = zero4;
#pragma unroll
  for (int nt = 0; nt < 16; nt++) {
    const short* bp =
        (const short*)ff1WT + (size_t)(nt * 16 + tq) * EMB + quad * 8;
    bf16x8 b0f = *(const bf16x8*)(bp);
    bf16x8 b1f = *(const bf16x8*)(bp + 32);
    bf16x8 b2f = *(const bf16x8*)(bp + 64);
    acc[nt] = __builtin_amdgcn_mfma_f32_16x16x32_bf16(a0, b0f, acc[nt], 0, 0, 0);
    acc[nt] = __builtin_amdgcn_mfma_f32_16x16x32_bf16(a1, b1f, acc[nt], 0, 0, 0);
    acc[nt] = __builtin_amdgcn_mfma_f32_16x16x32_bf16(a2, b2f, acc[nt], 0, 0, 0);
  }

  const int tok0 = m0 + quad * 4;
#pragma unroll
  for (int nt = 0; nt < 16; nt++) {
    int n = nt * 16 + tq;
    float bias = b1[n];
#pragma unroll
    for (int r = 0; r < 4; r++) {
      ffbf[(size_t)(tok0 + r) * FFDIM + n] =
          __float2bfloat16(fmaxf(acc[nt][r] + bias, 0.f));
    }
  }
}

// ---------------- Kernel 6: FF2 GEMM + residual + LN (MFMA) ----------------
__global__ __launch_bounds__(256) void ff2_ln_mfma_kernel(
    const __hip_bfloat16* __restrict__ ffbf,
    const __hip_bfloat16* __restrict__ ff2WT, const float* __restrict__ b2,
    const float* __restrict__ gamma, const float* __restrict__ beta,
    const float* __restrict__ hres, float* __restrict__ hout,
    __hip_bfloat16* __restrict__ hbf_out) {
  const int wave = threadIdx.x >> 6;
  const int lane = threadIdx.x & 63;
  const int tq = lane & 15;
  const int quad = lane >> 4;
  const int m0 = blockIdx.x * 64 + wave * 16;

  const short* ap = (const short*)ffbf + (size_t)(m0 + tq) * FFDIM;
  const short* bp = (const short*)ff2WT;

  f32x4 acc[6];
  const f32x4 zero4 = {0.f, 0.f, 0.f, 0.f};
#pragma unroll
  for (int dt = 0; dt < 6; dt++) acc[dt] = zero4;

#pragma unroll
  for (int kt = 0; kt < 8; kt++) {
    bf16x8 af = *(const bf16x8*)(ap + kt * 32 + quad * 8);
#pragma unroll
    for (int dt = 0; dt < 6; dt++) {
      bf16x8 bfr = *(const bf16x8*)(bp + (size_t)(dt * 16 + tq) * FFDIM +
                                    kt * 32 + quad * 8);
      acc[dt] = __builtin_amdgcn_mfma_f32_16x16x32_bf16(af, bfr, acc[dt], 0, 0, 0);
    }
  }

  const int tok0 = m0 + quad * 4;
  float s1[4] = {0.f, 0.f, 0.f, 0.f};
  float s2[4] = {0.f, 0.f, 0.f, 0.f};
#pragma unroll
  for (int dt = 0; dt < 6; dt++) {
    int n = dt * 16 + tq;
    float bias = b2[n];
#pragma unroll
    for (int r = 0; r < 4; r++) {
      float val = acc[dt][r] + bias + hres[(size_t)(tok0 + r) * EMB + n];
      acc[dt][r] = val;
      s1[r] += val;
      s2[r] += val * val;
    }
  }
#pragma unroll
  for (int mask = 1; mask < 16; mask <<= 1) {
#pragma unroll
    for (int r = 0; r < 4; r++) {
      s1[r] += __shfl_xor(s1[r], mask, 64);
      s2[r] += __shfl_xor(s2[r], mask, 64);
    }
  }
  float mean[4], rstd[4];
#pragma unroll
  for (int r = 0; r < 4; r++) {
    mean[r] = s1[r] * (1.0f / EMB);
    float var = s2[r] * (1.0f / EMB) - mean[r] * mean[r];
    rstd[r] = rsqrtf(var + EPSV);
  }
#pragma unroll
  for (int dt = 0; dt < 6; dt++) {
    int n = dt * 16 + tq;
    float g = gamma[n], bt = beta[n];
#pragma unroll
    for (int r = 0; r < 4; r++) {
      float o = (acc[dt][r] - mean[r]) * rstd[r] * g + bt;
      hout[(size_t)(tok0 + r) * EMB + n] = o;
      hbf_out[(size_t)(tok0 + r) * EMB + n] = __float2bfloat16(o);
    }
  }
}

// ---------------- launch ----------------------------------------------------
extern "C" void kernel_launch(void* const* d_in, const int* in_sizes, int n_in,
                              void* d_out, int out_size, void* d_ws,
                              size_t ws_size, hipStream_t stream) {
  const float* x = (const float*)d_in[0];
  const float* patch_W = (const float*)d_in[1];
  const float* patch_b = (const float*)d_in[2];
  const float* Wq = (const float*)d_in[3];
  const float* bq = (const float*)d_in[4];
  const float* Wk = (const float*)d_in[5];
  const float* bk = (const float*)d_in[6];
  const float* Wv = (const float*)d_in[7];
  const float* bv = (const float*)d_in[8];
  const float* Wo = (const float*)d_in[9];
  const float* bo = (const float*)d_in[10];
  const float* ff1_W = (const float*)d_in[11];
  const float* ff1_b = (const float*)d_in[12];
  const float* ff2_W = (const float*)d_in[13];
  const float* ff2_b = (const float*)d_in[14];
  const float* n1_g = (const float*)d_in[15];
  const float* n1_b = (const float*)d_in[16];
  const float* n2_g = (const float*)d_in[17];
  const float* n2_b = (const float*)d_in[18];

  // workspace layout (~202 MB)
  const size_t h_bytes = (size_t)TOK * EMB * sizeof(float);          // 13.76 MB
  const size_t hbf_bytes = (size_t)TOK * EMB * 2;                    // 6.88 MB
  const size_t kv_bytes = (size_t)CHUNK * NHEAD * SEQ * HDIM * 2;    // 41.29 MB
  const size_t heads_bytes = (size_t)TOK * NHEAD * HDIM * 2;         // 82.58 MB
  const size_t wqT_bytes = (size_t)NLAYER * NHEAD * HDIM * EMB * 2;  // 0.44 MB
  const size_t wkvT_bytes = 2 * wqT_bytes;                           // 0.88 MB
  const size_t woT_bytes = (size_t)NLAYER * EMB * NHEAD * HDIM * 2;  // 0.44 MB
  const size_t ffw_bytes = (size_t)NLAYER * FFDIM * EMB * 2;         // 0.10 MB
  char* ws = (char*)d_ws;
  size_t off = 0;
  float* h = (float*)(ws + off); off += h_bytes;
  float* hA = (float*)(ws + off); off += h_bytes;
  __hip_bfloat16* hbf = (__hip_bfloat16*)(ws + off); off += hbf_bytes;
  __hip_bfloat16* kbuf = (__hip_bfloat16*)(ws + off); off += kv_bytes;
  __hip_bfloat16* vbufT = (__hip_bfloat16*)(ws + off); off += kv_bytes;
  __hip_bfloat16* heads = (__hip_bfloat16*)(ws + off); off += heads_bytes;
  __hip_bfloat16* wqT = (__hip_bfloat16*)(ws + off); off += wqT_bytes;
  __hip_bfloat16* wkvT = (__hip_bfloat16*)(ws + off); off += wkvT_bytes;
  __hip_bfloat16* woT = (__hip_bfloat16*)(ws + off); off += woT_bytes;
  __hip_bfloat16* ff1WT = (__hip_bfloat16*)(ws + off); off += ffw_bytes;
  __hip_bfloat16* ff2WT = (__hip_bfloat16*)(ws + off); off += ffw_bytes;
  __hip_bfloat16* ffbf = (__hip_bfloat16*)kbuf;  // alias: free after attention

  wprep_kernel<<<dim3(NHEAD, 3, NLAYER), 256, 0, stream>>>(Wq, Wk, Wv, wqT, wkvT);
  woprep_kernel<<<NLAYER, 256, 0, stream>>>(Wo, woT);
  ffprep_kernel<<<dim3(2, NLAYER), 256, 0, stream>>>(ff1_W, ff2_W, ff1WT, ff2WT);
  patch_pe_kernel<<<(TOK * EMB + 255) / 256, 256, 0, stream>>>(x, patch_W,
                                                               patch_b, h, hbf);

  for (int l = 0; l < NLAYER; l++) {
    const __hip_bfloat16* wqT_l = wqT + (size_t)l * NHEAD * HDIM * EMB;
    const __hip_bfloat16* wkvT_l = wkvT + (size_t)l * 2 * NHEAD * HDIM * EMB;
    const __hip_bfloat16* woT_l = woT + (size_t)l * EMB * NHEAD * HDIM;
    const __hip_bfloat16* ff1WT_l = ff1WT + (size_t)l * FFDIM * EMB;
    const __hip_bfloat16* ff2WT_l = ff2WT + (size_t)l * EMB * FFDIM;
    const float* bq_l = bq + (size_t)l * NHEAD * HDIM;
    const float* bk_l = bk + (size_t)l * NHEAD * HDIM;
    const float* bv_l = bv + (size_t)l * NHEAD * HDIM;
    const float* bo_l = bo + (size_t)l * EMB;

    for (int c = 0; c < BATCH / CHUNK; c++) {
      int b0 = c * CHUNK;
      kv_mfma_kernel<<<dim3(CHUNK * SEQ / 64, 2 * NHEAD * HDIM / 64), 256, 0,
                       stream>>>(hbf, wkvT_l, bk_l, bv_l, kbuf, vbufT, b0);
      attn_mfma_kernel<<<9 * NHEAD * CHUNK, 256, 0, stream>>>(
          hbf, wqT_l, bq_l, kbuf, vbufT, heads, b0);
    }
    // LN1: reads residual h, writes hA (fp32) + hbf (bf16)
    wo_ln_mfma_kernel<<<TOK / 64, 256, 0, stream>>>(
        heads, woT_l, bo_l, n1_g + l * EMB, n1_b + l * EMB, h, hA, hbf);
    // FF path (MFMA): ff1 reads hbf -> ffbf; ff2 reads ffbf + hA residual
    ff1_mfma_kernel<<<TOK / 64, 256, 0, stream>>>(hbf, ff1WT_l,
                                                  ff1_b + l * FFDIM, ffbf);
    float* dst = (l == NLAYER - 1) ? (float*)d_out : h;
    ff2_ln_mfma_kernel<<<TOK / 64, 256, 0, stream>>>(
        ffbf, ff2WT_l, ff2_b + l * EMB, n2_g + l * EMB, n2_b + l * EMB, hA,
        dst, hbf);
  }
}

// Round 12
// 1402.942 us; speedup vs baseline: 1.1510x; 1.1322x over previous
//
#include <hip/hip_runtime.h>
#include <hip/hip_bf16.h>
#include <math.h>

#define BATCH 64
#define CHUNK 32           // batch chunk for k/v scratch
#define INPUT_SIZE 10080
#define PATCH 18
#define SEQ 560            // S
#define EMB 96             // E
#define NHEAD 12           // H
#define HDIM 96            // D
#define FFDIM 256          // F
#define NLAYER 2
#define TOK (BATCH * SEQ)  // 35840 tokens
#define EPSV 1e-5f
#define SCALE 0.10206207261596577f  // 1/sqrt(96)

typedef __attribute__((ext_vector_type(8))) short bf16x8;  // 8 bf16 (4 VGPRs)
typedef __attribute__((ext_vector_type(4))) short bf16x4;  // 4 bf16 (8B store)
typedef __attribute__((ext_vector_type(4))) float f32x4;   // 4 fp32 acc

static __device__ __forceinline__ short f2bf(float x) {
  union { __hip_bfloat16 b; short s; } u;
  u.b = __float2bfloat16(x);
  return u.s;
}

// ---------------- Kernel 0a: QKV weight transpose prep ---------------------
// wqT:  [L][H][D][E] bf16 ; wkvT: [L][2*H*D][E] bf16 (k rows then v rows)
__global__ __launch_bounds__(256) void wprep_kernel(
    const float* __restrict__ Wq, const float* __restrict__ Wk,
    const float* __restrict__ Wv, __hip_bfloat16* __restrict__ wqT,
    __hip_bfloat16* __restrict__ wkvT) {
  int hh = blockIdx.x, mat = blockIdx.y, l = blockIdx.z;
  const float* src =
      (mat == 0 ? Wq : (mat == 1 ? Wk : Wv)) + ((size_t)l * NHEAD + hh) * EMB * HDIM;
  __shared__ float t[HDIM * 97];
  for (int i = threadIdx.x; i < EMB * HDIM; i += 256) {
    int e = i / HDIM, d = i % HDIM;
    t[d * 97 + e] = src[i];
  }
  __syncthreads();
  __hip_bfloat16* dst;
  if (mat == 0)
    dst = wqT + ((size_t)l * NHEAD + hh) * HDIM * EMB;
  else
    dst = wkvT + ((size_t)l * 2 * NHEAD * HDIM + (mat - 1) * NHEAD * HDIM +
                  hh * HDIM) * EMB;
  for (int j = threadIdx.x; j < HDIM * EMB; j += 256) {
    int d = j / EMB, e = j % EMB;
    dst[j] = __float2bfloat16(t[d * 97 + e]);
  }
}

// ---------------- Kernel 0b: Wo transpose prep -----------------------------
// woT: [L][E=96][HD=1152]   (Wo is [L][1152][96])
__global__ __launch_bounds__(256) void woprep_kernel(
    const float* __restrict__ Wo, __hip_bfloat16* __restrict__ woT) {
  int l = blockIdx.x;
  const float* src = Wo + (size_t)l * NHEAD * HDIM * EMB;
  __hip_bfloat16* dst = woT + (size_t)l * EMB * NHEAD * HDIM;
  for (int i = threadIdx.x; i < EMB * NHEAD * HDIM; i += 256) {
    int e = i / (NHEAD * HDIM), j = i % (NHEAD * HDIM);
    dst[i] = __float2bfloat16(src[(size_t)j * EMB + e]);
  }
}

// ---------------- Kernel 0c: FF weight transpose prep ----------------------
// ff1WT: [L][F=256][E=96]  (ff1_W is [L][96][256]) ; ff2WT: [L][E=96][F=256]
__global__ __launch_bounds__(256) void ffprep_kernel(
    const float* __restrict__ ff1_W, const float* __restrict__ ff2_W,
    __hip_bfloat16* __restrict__ ff1WT, __hip_bfloat16* __restrict__ ff2WT) {
  int mat = blockIdx.x, l = blockIdx.y;
  if (mat == 0) {
    const float* src = ff1_W + (size_t)l * EMB * FFDIM;
    __hip_bfloat16* dst = ff1WT + (size_t)l * FFDIM * EMB;
    for (int i = threadIdx.x; i < FFDIM * EMB; i += 256) {
      int f = i / EMB, e = i % EMB;
      dst[i] = __float2bfloat16(src[(size_t)e * FFDIM + f]);
    }
  } else {
    const float* src = ff2_W + (size_t)l * FFDIM * EMB;
    __hip_bfloat16* dst = ff2WT + (size_t)l * EMB * FFDIM;
    for (int i = threadIdx.x; i < EMB * FFDIM; i += 256) {
      int e = i / FFDIM, f = i % FFDIM;
      dst[i] = __float2bfloat16(src[(size_t)f * EMB + e]);
    }
  }
}

// ---------------- Kernel 1: patch embedding + sinusoidal PE ----------------
__global__ void patch_pe_kernel(const float* __restrict__ x,
                                const float* __restrict__ W,
                                const float* __restrict__ bias,
                                float* __restrict__ h,
                                __hip_bfloat16* __restrict__ hbf) {
  int gid = blockIdx.x * blockDim.x + threadIdx.x;
  if (gid >= TOK * EMB) return;
  int tok = gid / EMB;
  int e = gid % EMB;
  int b = tok / SEQ;
  int s = tok % SEQ;
  const float* xp = x + b * INPUT_SIZE + s * PATCH;
  float acc = bias[e];
#pragma unroll
  for (int p = 0; p < PATCH; p++) acc += xp[p] * W[p * EMB + e];
  int i = e >> 1;
  float freq = __expf(-(float)(2 * i) * (9.210340371976184f / 96.0f));
  float ang = (float)s * freq;
  acc += (e & 1) ? cosf(ang) : sinf(ang);
  h[gid] = acc;
  hbf[gid] = __float2bfloat16(acc);
}

// ---------------- Kernel 2: K/V projection GEMM (MFMA) ---------------------
// K half -> kbuf[bh][s][d] via wave-local LDS bounce -> coalesced 16B rows.
// V half -> vbufT[bh][d][t] via 8B packed stores.
__global__ __launch_bounds__(256) void kv_mfma_kernel(
    const __hip_bfloat16* __restrict__ hbf,
    const __hip_bfloat16* __restrict__ wkvT, const float* __restrict__ bk,
    const float* __restrict__ bv, __hip_bfloat16* __restrict__ kbuf,
    __hip_bfloat16* __restrict__ vbufT, int b0) {
  const int wave = threadIdx.x >> 6;
  const int lane = threadIdx.x & 63;
  const int tq = lane & 15;
  const int quad = lane >> 4;
  const int m0 = blockIdx.x * 64 + wave * 16;  // token tile row (chunk-local)
  const int n0 = blockIdx.y * 64;

  __shared__ short tile[4][16][68];  // wave-local K bounce (8.7 KB)

  const short* ap =
      (const short*)hbf + ((size_t)b0 * SEQ + m0 + tq) * EMB + quad * 8;
  bf16x8 a0 = *(const bf16x8*)(ap);
  bf16x8 a1 = *(const bf16x8*)(ap + 32);
  bf16x8 a2 = *(const bf16x8*)(ap + 64);

  f32x4 acc[4];
  const f32x4 zero4 = {0.f, 0.f, 0.f, 0.f};
#pragma unroll
  for (int nt = 0; nt < 4; nt++) acc[nt] = zero4;
#pragma unroll
  for (int nt = 0; nt < 4; nt++) {
    const short* bp =
        (const short*)wkvT + (size_t)(n0 + nt * 16 + tq) * EMB + quad * 8;
    bf16x8 b0f = *(const bf16x8*)(bp);
    bf16x8 b1f = *(const bf16x8*)(bp + 32);
    bf16x8 b2f = *(const bf16x8*)(bp + 64);
    acc[nt] = __builtin_amdgcn_mfma_f32_16x16x32_bf16(a0, b0f, acc[nt], 0, 0, 0);
    acc[nt] = __builtin_amdgcn_mfma_f32_16x16x32_bf16(a1, b1f, acc[nt], 0, 0, 0);
    acc[nt] = __builtin_amdgcn_mfma_f32_16x16x32_bf16(a2, b2f, acc[nt], 0, 0, 0);
  }

  // rows are tokens tl = m0 + quad*4 + j (j=0..3): same batch, s consecutive
  const int tl0 = m0 + quad * 4;
  const int blb = tl0 / SEQ;
  const int ss0 = tl0 - blb * SEQ;

  if (n0 < NHEAD * HDIM) {
    // ---- K tile: bias -> LDS (wave-local) -> coalesced bf16x8 stores ----
#pragma unroll
    for (int nt = 0; nt < 4; nt++) {
      int n = n0 + nt * 16 + tq;  // == r (kv=0), head hh=n/96, d=n%96
      float bias = bk[n];
#pragma unroll
      for (int j = 0; j < 4; j++)
        tile[wave][quad * 4 + j][nt * 16 + tq] = f2bf(acc[nt][j] + bias);
    }
    // wave-local LDS: compiler-inserted lgkmcnt orders write->read
#pragma unroll
    for (int it = 0; it < 2; it++) {
      int idx = it * 64 + lane;
      int row = idx >> 3;   // 0..15 token row
      int seg = idx & 7;    // 8-short segment (never crosses head: 96%8==0)
      int tl = m0 + row;
      int bb = tl / SEQ;
      int ss = tl - bb * SEQ;
      int r0s = n0 + seg * 8;
      int hh2 = r0s / HDIM;
      int d0 = r0s - hh2 * HDIM;
      bf16x8 v = *(const bf16x8*)&tile[wave][row][seg * 8];
      *(bf16x8*)((short*)kbuf +
                 ((size_t)(bb * NHEAD + hh2) * SEQ + ss) * HDIM + d0) = v;
    }
  } else {
    // ---- V tile: packed 8B stores into vbufT[bh][d][t] ----
#pragma unroll
    for (int nt = 0; nt < 4; nt++) {
      int n = n0 + nt * 16 + tq;
      int r = n - NHEAD * HDIM;  // h*96+d
      int hh2 = r / HDIM;
      int d = r - hh2 * HDIM;
      float bias = bv[r];
      bf16x4 pack;
#pragma unroll
      for (int j = 0; j < 4; j++) pack[j] = f2bf(acc[nt][j] + bias);
      *(bf16x4*)((short*)vbufT +
                 ((size_t)(blb * NHEAD + hh2) * HDIM + d) * SEQ + ss0) = pack;
    }
  }
}

// ---------------- Kernel 3: MFMA attention with LDS K staging (round 9) ----
// 1D grid of 9*NHEAD*CHUNK blocks with XCD swizzle. LDS lifetimes:
// (1) Q staging (wave-local) -> (2) K staging for score phase (cooperative,
// 2 halves, padded stride) -> (3) P staging for PV (wave-local).
#define PSTRIDE 584  // Q/P view row stride (shorts)
#define KSTR 104     // K view row stride (shorts): 208B, 16B-aligned
__global__ __launch_bounds__(256, 2) void attn_mfma_kernel(
    const __hip_bfloat16* __restrict__ hbf,
    const __hip_bfloat16* __restrict__ wqT, const float* __restrict__ bq,
    const __hip_bfloat16* __restrict__ kbuf,
    const __hip_bfloat16* __restrict__ vbufT,
    __hip_bfloat16* __restrict__ heads, int b0) {
  const int flat = blockIdx.x;
  const int xcd = flat & 7;
  const int slot = flat >> 3;
  const int g = (slot / 9) * 8 + xcd;  // 0..383 group = (bl,hh)
  const int qt = slot % 9;             // 0..8
  const int hh = g % NHEAD;
  const int bl = g / NHEAD;            // local batch 0..31
  const int wave = threadIdx.x >> 6;
  const int lane = threadIdx.x & 63;
  const int tq = lane & 15;
  const int quad = lane >> 4;

  __shared__ __align__(16) short sbuf[4 * 16 * PSTRIDE];  // 74752 B
  short* pw = sbuf + wave * 16 * PSTRIDE;  // wave's Q/P region [16][PSTRIDE]

  const size_t bh = (size_t)(bl * NHEAD + hh);
  const short* kb = (const short*)kbuf + bh * SEQ * HDIM;
  const short* vb = (const short*)vbufT + bh * HDIM * SEQ;

  // ---- (1) Q projection via MFMA: 16 q rows x 96 d ----
  const int q0 = qt * 64 + wave * 16;
  int qrow = q0 + tq;
  if (qrow > SEQ - 1) qrow = SEQ - 1;
  const short* hp =
      (const short*)hbf + ((size_t)(b0 + bl) * SEQ + qrow) * EMB + quad * 8;
  bf16x8 ha0 = *(const bf16x8*)(hp);
  bf16x8 ha1 = *(const bf16x8*)(hp + 32);
  bf16x8 ha2 = *(const bf16x8*)(hp + 64);
  const f32x4 zero4 = {0.f, 0.f, 0.f, 0.f};
  f32x4 qacc[6];
#pragma unroll
  for (int dt = 0; dt < 6; dt++) qacc[dt] = zero4;
#pragma unroll
  for (int dt = 0; dt < 6; dt++) {
    const short* wp = (const short*)wqT +
                      ((size_t)hh * HDIM + dt * 16 + tq) * EMB + quad * 8;
    bf16x8 w0 = *(const bf16x8*)(wp);
    bf16x8 w1 = *(const bf16x8*)(wp + 32);
    bf16x8 w2 = *(const bf16x8*)(wp + 64);
    qacc[dt] = __builtin_amdgcn_mfma_f32_16x16x32_bf16(ha0, w0, qacc[dt], 0, 0, 0);
    qacc[dt] = __builtin_amdgcn_mfma_f32_16x16x32_bf16(ha1, w1, qacc[dt], 0, 0, 0);
    qacc[dt] = __builtin_amdgcn_mfma_f32_16x16x32_bf16(ha2, w2, qacc[dt], 0, 0, 0);
  }
  // stage Q (C-layout) into pw cols 0..95, re-read as A-frags (wave-local)
#pragma unroll
  for (int dt = 0; dt < 6; dt++) {
    int d = dt * 16 + tq;
    float bias = bq[hh * HDIM + d];
#pragma unroll
    for (int r = 0; r < 4; r++)
      pw[(quad * 4 + r) * PSTRIDE + d] = f2bf((qacc[dt][r] + bias) * SCALE);
  }
  bf16x8 aq0 = *(const bf16x8*)&pw[tq * PSTRIDE + quad * 8];
  bf16x8 aq1 = *(const bf16x8*)&pw[tq * PSTRIDE + quad * 8 + 32];
  bf16x8 aq2 = *(const bf16x8*)&pw[tq * PSTRIDE + quad * 8 + 64];
  __syncthreads();  // all waves have Q in regs; sbuf free for K staging

  f32x4 acc[35];
#pragma unroll
  for (int tt = 0; tt < 35; tt++) acc[tt] = zero4;

  // ---- (2a) stage K rows [0,288) and compute score tiles 0..17 ----
  for (int i = threadIdx.x; i < 288 * 12; i += 256) {
    int row = i / 12, gg = i - row * 12;
    *(bf16x8*)&sbuf[row * KSTR + gg * 8] =
        *(const bf16x8*)(kb + (size_t)row * HDIM + gg * 8);
  }
  __syncthreads();
#pragma unroll
  for (int tt = 0; tt < 18; tt++) {
    const short* kp = &sbuf[(tt * 16 + tq) * KSTR + quad * 8];
    bf16x8 kb0 = *(const bf16x8*)(kp);
    bf16x8 kb1 = *(const bf16x8*)(kp + 32);
    bf16x8 kb2 = *(const bf16x8*)(kp + 64);
    acc[tt] = __builtin_amdgcn_mfma_f32_16x16x32_bf16(aq0, kb0, acc[tt], 0, 0, 0);
    acc[tt] = __builtin_amdgcn_mfma_f32_16x16x32_bf16(aq1, kb1, acc[tt], 0, 0, 0);
    acc[tt] = __builtin_amdgcn_mfma_f32_16x16x32_bf16(aq2, kb2, acc[tt], 0, 0, 0);
  }
  __syncthreads();

  // ---- (2b) stage K rows [288,560) and compute score tiles 18..34 ----
  for (int i = threadIdx.x; i < 272 * 12; i += 256) {
    int row = i / 12, gg = i - row * 12;
    *(bf16x8*)&sbuf[row * KSTR + gg * 8] =
        *(const bf16x8*)(kb + (size_t)(288 + row) * HDIM + gg * 8);
  }
  __syncthreads();
#pragma unroll
  for (int tt = 18; tt < 35; tt++) {
    const short* kp = &sbuf[(tt * 16 + tq - 288) * KSTR + quad * 8];
    bf16x8 kb0 = *(const bf16x8*)(kp);
    bf16x8 kb1 = *(const bf16x8*)(kp + 32);
    bf16x8 kb2 = *(const bf16x8*)(kp + 64);
    acc[tt] = __builtin_amdgcn_mfma_f32_16x16x32_bf16(aq0, kb0, acc[tt], 0, 0, 0);
    acc[tt] = __builtin_amdgcn_mfma_f32_16x16x32_bf16(aq1, kb1, acc[tt], 0, 0, 0);
    acc[tt] = __builtin_amdgcn_mfma_f32_16x16x32_bf16(aq2, kb2, acc[tt], 0, 0, 0);
  }

  // ---- softmax ----
  float m0 = -1e30f, m1 = -1e30f, m2 = -1e30f, m3 = -1e30f;
#pragma unroll
  for (int tt = 0; tt < 35; tt++) {
    m0 = fmaxf(m0, acc[tt][0]);
    m1 = fmaxf(m1, acc[tt][1]);
    m2 = fmaxf(m2, acc[tt][2]);
    m3 = fmaxf(m3, acc[tt][3]);
  }
#pragma unroll
  for (int mask = 1; mask < 16; mask <<= 1) {
    m0 = fmaxf(m0, __shfl_xor(m0, mask, 64));
    m1 = fmaxf(m1, __shfl_xor(m1, mask, 64));
    m2 = fmaxf(m2, __shfl_xor(m2, mask, 64));
    m3 = fmaxf(m3, __shfl_xor(m3, mask, 64));
  }
  float l0 = 0.f, l1 = 0.f, l2 = 0.f, l3 = 0.f;
#pragma unroll
  for (int tt = 0; tt < 35; tt++) {
    float p0 = __expf(acc[tt][0] - m0); acc[tt][0] = p0; l0 += p0;
    float p1 = __expf(acc[tt][1] - m1); acc[tt][1] = p1; l1 += p1;
    float p2 = __expf(acc[tt][2] - m2); acc[tt][2] = p2; l2 += p2;
    float p3 = __expf(acc[tt][3] - m3); acc[tt][3] = p3; l3 += p3;
  }
#pragma unroll
  for (int mask = 1; mask < 16; mask <<= 1) {
    l0 += __shfl_xor(l0, mask, 64);
    l1 += __shfl_xor(l1, mask, 64);
    l2 += __shfl_xor(l2, mask, 64);
    l3 += __shfl_xor(l3, mask, 64);
  }
  __syncthreads();  // all waves done reading K from sbuf

  // ---- (3) P -> pw (A-layout, unnormalized; wave-local) ----
  for (int i = lane; i < 256; i += 64)
    pw[(i >> 4) * PSTRIDE + 560 + (i & 15)] = 0;  // zero t-pad cols 560..575
#pragma unroll
  for (int tt = 0; tt < 35; tt++) {
    int col = tt * 16 + tq;
    pw[(quad * 4 + 0) * PSTRIDE + col] = f2bf(acc[tt][0]);
    pw[(quad * 4 + 1) * PSTRIDE + col] = f2bf(acc[tt][1]);
    pw[(quad * 4 + 2) * PSTRIDE + col] = f2bf(acc[tt][2]);
    pw[(quad * 4 + 3) * PSTRIDE + col] = f2bf(acc[tt][3]);
  }

  // ---- PV (wave-local) ----
  f32x4 oacc[6];
#pragma unroll
  for (int dt = 0; dt < 6; dt++) oacc[dt] = zero4;
#pragma unroll
  for (int kt = 0; kt < 18; kt++) {
    bf16x8 pa = *(const bf16x8*)&pw[tq * PSTRIDE + kt * 32 + quad * 8];
#pragma unroll
    for (int dt = 0; dt < 6; dt++) {
      const short* vp = vb + (size_t)(dt * 16 + tq) * SEQ + kt * 32 + quad * 8;
      bf16x8 vf = *(const bf16x8*)vp;
      oacc[dt] = __builtin_amdgcn_mfma_f32_16x16x32_bf16(pa, vf, oacc[dt], 0, 0, 0);
    }
  }

  // ---- normalize + store ----
  float r0 = 1.f / l0, r1 = 1.f / l1, r2 = 1.f / l2, r3 = 1.f / l3;
  int qg = q0 + quad * 4;
  __hip_bfloat16* hpout =
      heads + ((size_t)(b0 + bl) * SEQ) * (NHEAD * HDIM) + (size_t)hh * HDIM;
#pragma unroll
  for (int dt = 0; dt < 6; dt++) {
    int d = dt * 16 + tq;
    if (qg + 0 < SEQ) hpout[(size_t)(qg + 0) * (NHEAD * HDIM) + d] = __float2bfloat16(oacc[dt][0] * r0);
    if (qg + 1 < SEQ) hpout[(size_t)(qg + 1) * (NHEAD * HDIM) + d] = __float2bfloat16(oacc[dt][1] * r1);
    if (qg + 2 < SEQ) hpout[(size_t)(qg + 2) * (NHEAD * HDIM) + d] = __float2bfloat16(oacc[dt][2] * r2);
    if (qg + 3 < SEQ) hpout[(size_t)(qg + 3) * (NHEAD * HDIM) + d] = __float2bfloat16(oacc[dt][3] * r3);
  }
}

// ---------------- Kernel 4: Wo GEMM + residual + LayerNorm (MFMA, proven) --
__global__ __launch_bounds__(256) void wo_ln_mfma_kernel(
    const __hip_bfloat16* __restrict__ heads,
    const __hip_bfloat16* __restrict__ woT, const float* __restrict__ bo,
    const float* __restrict__ gamma, const float* __restrict__ beta,
    const float* __restrict__ hres, float* __restrict__ hA,
    __hip_bfloat16* __restrict__ hbf) {
  const int wave = threadIdx.x >> 6;
  const int lane = threadIdx.x & 63;
  const int tq = lane & 15;
  const int quad = lane >> 4;
  const int m0 = blockIdx.x * 64 + wave * 16;

  const short* ap = (const short*)heads + (size_t)(m0 + tq) * (NHEAD * HDIM);
  const short* bp = (const short*)woT;

  f32x4 acc[6];
  const f32x4 zero4 = {0.f, 0.f, 0.f, 0.f};
#pragma unroll
  for (int dt = 0; dt < 6; dt++) acc[dt] = zero4;

  for (int kt = 0; kt < 36; kt++) {
    bf16x8 af = *(const bf16x8*)(ap + kt * 32 + quad * 8);
#pragma unroll
    for (int dt = 0; dt < 6; dt++) {
      bf16x8 bfr = *(const bf16x8*)(bp + (size_t)(dt * 16 + tq) * (NHEAD * HDIM) +
                                    kt * 32 + quad * 8);
      acc[dt] = __builtin_amdgcn_mfma_f32_16x16x32_bf16(af, bfr, acc[dt], 0, 0, 0);
    }
  }

  const int tok0 = m0 + quad * 4;
  float s1[4] = {0.f, 0.f, 0.f, 0.f};
  float s2[4] = {0.f, 0.f, 0.f, 0.f};
#pragma unroll
  for (int dt = 0; dt < 6; dt++) {
    int n = dt * 16 + tq;
    float bias = bo[n];
#pragma unroll
    for (int r = 0; r < 4; r++) {
      float val = acc[dt][r] + bias + hres[(size_t)(tok0 + r) * EMB + n];
      acc[dt][r] = val;
      s1[r] += val;
      s2[r] += val * val;
    }
  }
#pragma unroll
  for (int mask = 1; mask < 16; mask <<= 1) {
#pragma unroll
    for (int r = 0; r < 4; r++) {
      s1[r] += __shfl_xor(s1[r], mask, 64);
      s2[r] += __shfl_xor(s2[r], mask, 64);
    }
  }
  float mean[4], rstd[4];
#pragma unroll
  for (int r = 0; r < 4; r++) {
    mean[r] = s1[r] * (1.0f / EMB);
    float var = s2[r] * (1.0f / EMB) - mean[r] * mean[r];
    rstd[r] = rsqrtf(var + EPSV);
  }
#pragma unroll
  for (int dt = 0; dt < 6; dt++) {
    int n = dt * 16 + tq;
    float g = gamma[n], bt = beta[n];
#pragma unroll
    for (int r = 0; r < 4; r++) {
      float o = (acc[dt][r] - mean[r]) * rstd[r] * g + bt;
      hA[(size_t)(tok0 + r) * EMB + n] = o;
      hbf[(size_t)(tok0 + r) * EMB + n] = __float2bfloat16(o);
    }
  }
}

// ---------------- Kernel 5: FF1 GEMM + ReLU (MFMA) -------------------------
__global__ __launch_bounds__(256) void ff1_mfma_kernel(
    const __hip_bfloat16* __restrict__ hbf,
    const __hip_bfloat16* __restrict__ ff1WT, const float* __restrict__ b1,
    __hip_bfloat16* __restrict__ ffbf) {
  const int wave = threadIdx.x >> 6;
  const int lane = threadIdx.x & 63;
  const int tq = lane & 15;
  const int quad = lane >> 4;
  const int m0 = blockIdx.x * 64 + wave * 16;

  const short* ap = (const short*)hbf + (size_t)(m0 + tq) * EMB + quad * 8;
  bf16x8 a0 = *(const bf16x8*)(ap);
  bf16x8 a1 = *(const bf16x8*)(ap + 32);
  bf16x8 a2 = *(const bf16x8*)(ap + 64);

  f32x4 acc[16];
  const f32x4 zero4 = {0.f, 0.f, 0.f, 0.f};
#pragma unroll
  for (int nt = 0; nt < 16; nt++) acc[nt] = zero4;
#pragma unroll
  for (int nt = 0; nt < 16; nt++) {
    const short* bp =
        (const short*)ff1WT + (size_t)(nt * 16 + tq) * EMB + quad * 8;
    bf16x8 b0f = *(const bf16x8*)(bp);
    bf16x8 b1f = *(const bf16x8*)(bp + 32);
    bf16x8 b2f = *(const bf16x8*)(bp + 64);
    acc[nt] = __builtin_amdgcn_mfma_f32_16x16x32_bf16(a0, b0f, acc[nt], 0, 0, 0);
    acc[nt] = __builtin_amdgcn_mfma_f32_16x16x32_bf16(a1, b1f, acc[nt], 0, 0, 0);
    acc[nt] = __builtin_amdgcn_mfma_f32_16x16x32_bf16(a2, b2f, acc[nt], 0, 0, 0);
  }

  const int tok0 = m0 + quad * 4;
#pragma unroll
  for (int nt = 0; nt < 16; nt++) {
    int n = nt * 16 + tq;
    float bias = b1[n];
#pragma unroll
    for (int r = 0; r < 4; r++) {
      ffbf[(size_t)(tok0 + r) * FFDIM + n] =
          __float2bfloat16(fmaxf(acc[nt][r] + bias, 0.f));
    }
  }
}

// ---------------- Kernel 6: FF2 GEMM + residual + LN (MFMA) ----------------
__global__ __launch_bounds__(256) void ff2_ln_mfma_kernel(
    const __hip_bfloat16* __restrict__ ffbf,
    const __hip_bfloat16* __restrict__ ff2WT, const float* __restrict__ b2,
    const float* __restrict__ gamma, const float* __restrict__ beta,
    const float* __restrict__ hres, float* __restrict__ hout,
    __hip_bfloat16* __restrict__ hbf_out) {
  const int wave = threadIdx.x >> 6;
  const int lane = threadIdx.x & 63;
  const int tq = lane & 15;
  const int quad = lane >> 4;
  const int m0 = blockIdx.x * 64 + wave * 16;

  const short* ap = (const short*)ffbf + (size_t)(m0 + tq) * FFDIM;
  const short* bp = (const short*)ff2WT;

  f32x4 acc[6];
  const f32x4 zero4 = {0.f, 0.f, 0.f, 0.f};
#pragma unroll
  for (int dt = 0; dt < 6; dt++) acc[dt] = zero4;

#pragma unroll
  for (int kt = 0; kt < 8; kt++) {
    bf16x8 af = *(const bf16x8*)(ap + kt * 32 + quad * 8);
#pragma unroll
    for (int dt = 0; dt < 6; dt++) {
      bf16x8 bfr = *(const bf16x8*)(bp + (size_t)(dt * 16 + tq) * FFDIM +
                                    kt * 32 + quad * 8);
      acc[dt] = __builtin_amdgcn_mfma_f32_16x16x32_bf16(af, bfr, acc[dt], 0, 0, 0);
    }
  }

  const int tok0 = m0 + quad * 4;
  float s1[4] = {0.f, 0.f, 0.f, 0.f};
  float s2[4] = {0.f, 0.f, 0.f, 0.f};
#pragma unroll
  for (int dt = 0; dt < 6; dt++) {
    int n = dt * 16 + tq;
    float bias = b2[n];
#pragma unroll
    for (int r = 0; r < 4; r++) {
      float val = acc[dt][r] + bias + hres[(size_t)(tok0 + r) * EMB + n];
      acc[dt][r] = val;
      s1[r] += val;
      s2[r] += val * val;
    }
  }
#pragma unroll
  for (int mask = 1; mask < 16; mask <<= 1) {
#pragma unroll
    for (int r = 0; r < 4; r++) {
      s1[r] += __shfl_xor(s1[r], mask, 64);
      s2[r] += __shfl_xor(s2[r], mask, 64);
    }
  }
  float mean[4], rstd[4];
#pragma unroll
  for (int r = 0; r < 4; r++) {
    mean[r] = s1[r] * (1.0f / EMB);
    float var = s2[r] * (1.0f / EMB) - mean[r] * mean[r];
    rstd[r] = rsqrtf(var + EPSV);
  }
#pragma unroll
  for (int dt = 0; dt < 6; dt++) {
    int n = dt * 16 + tq;
    float g = gamma[n], bt = beta[n];
#pragma unroll
    for (int r = 0; r < 4; r++) {
      float o = (acc[dt][r] - mean[r]) * rstd[r] * g + bt;
      hout[(size_t)(tok0 + r) * EMB + n] = o;
      hbf_out[(size_t)(tok0 + r) * EMB + n] = __float2bfloat16(o);
    }
  }
}

// ---------------- launch ----------------------------------------------------
extern "C" void kernel_launch(void* const* d_in, const int* in_sizes, int n_in,
                              void* d_out, int out_size, void* d_ws,
                              size_t ws_size, hipStream_t stream) {
  const float* x = (const float*)d_in[0];
  const float* patch_W = (const float*)d_in[1];
  const float* patch_b = (const float*)d_in[2];
  const float* Wq = (const float*)d_in[3];
  const float* bq = (const float*)d_in[4];
  const float* Wk = (const float*)d_in[5];
  const float* bk = (const float*)d_in[6];
  const float* Wv = (const float*)d_in[7];
  const float* bv = (const float*)d_in[8];
  const float* Wo = (const float*)d_in[9];
  const float* bo = (const float*)d_in[10];
  const float* ff1_W = (const float*)d_in[11];
  const float* ff1_b = (const float*)d_in[12];
  const float* ff2_W = (const float*)d_in[13];
  const float* ff2_b = (const float*)d_in[14];
  const float* n1_g = (const float*)d_in[15];
  const float* n1_b = (const float*)d_in[16];
  const float* n2_g = (const float*)d_in[17];
  const float* n2_b = (const float*)d_in[18];

  // workspace layout (~202 MB)
  const size_t h_bytes = (size_t)TOK * EMB * sizeof(float);          // 13.76 MB
  const size_t hbf_bytes = (size_t)TOK * EMB * 2;                    // 6.88 MB
  const size_t kv_bytes = (size_t)CHUNK * NHEAD * SEQ * HDIM * 2;    // 41.29 MB
  const size_t heads_bytes = (size_t)TOK * NHEAD * HDIM * 2;         // 82.58 MB
  const size_t wqT_bytes = (size_t)NLAYER * NHEAD * HDIM * EMB * 2;  // 0.44 MB
  const size_t wkvT_bytes = 2 * wqT_bytes;                           // 0.88 MB
  const size_t woT_bytes = (size_t)NLAYER * EMB * NHEAD * HDIM * 2;  // 0.44 MB
  const size_t ffw_bytes = (size_t)NLAYER * FFDIM * EMB * 2;         // 0.10 MB
  char* ws = (char*)d_ws;
  size_t off = 0;
  float* h = (float*)(ws + off); off += h_bytes;
  float* hA = (float*)(ws + off); off += h_bytes;
  __hip_bfloat16* hbf = (__hip_bfloat16*)(ws + off); off += hbf_bytes;
  __hip_bfloat16* kbuf = (__hip_bfloat16*)(ws + off); off += kv_bytes;
  __hip_bfloat16* vbufT = (__hip_bfloat16*)(ws + off); off += kv_bytes;
  __hip_bfloat16* heads = (__hip_bfloat16*)(ws + off); off += heads_bytes;
  __hip_bfloat16* wqT = (__hip_bfloat16*)(ws + off); off += wqT_bytes;
  __hip_bfloat16* wkvT = (__hip_bfloat16*)(ws + off); off += wkvT_bytes;
  __hip_bfloat16* woT = (__hip_bfloat16*)(ws + off); off += woT_bytes;
  __hip_bfloat16* ff1WT = (__hip_bfloat16*)(ws + off); off += ffw_bytes;
  __hip_bfloat16* ff2WT = (__hip_bfloat16*)(ws + off); off += ffw_bytes;
  __hip_bfloat16* ffbf = (__hip_bfloat16*)kbuf;  // alias: free after attention

  wprep_kernel<<<dim3(NHEAD, 3, NLAYER), 256, 0, stream>>>(Wq, Wk, Wv, wqT, wkvT);
  woprep_kernel<<<NLAYER, 256, 0, stream>>>(Wo, woT);
  ffprep_kernel<<<dim3(2, NLAYER), 256, 0, stream>>>(ff1_W, ff2_W, ff1WT, ff2WT);
  patch_pe_kernel<<<(TOK * EMB + 255) / 256, 256, 0, stream>>>(x, patch_W,
                                                               patch_b, h, hbf);

  for (int l = 0; l < NLAYER; l++) {
    const __hip_bfloat16* wqT_l = wqT + (size_t)l * NHEAD * HDIM * EMB;
    const __hip_bfloat16* wkvT_l = wkvT + (size_t)l * 2 * NHEAD * HDIM * EMB;
    const __hip_bfloat16* woT_l = woT + (size_t)l * EMB * NHEAD * HDIM;
    const __hip_bfloat16* ff1WT_l = ff1WT + (size_t)l * FFDIM * EMB;
    const __hip_bfloat16* ff2WT_l = ff2WT + (size_t)l * EMB * FFDIM;
    const float* bq_l = bq + (size_t)l * NHEAD * HDIM;
    const float* bk_l = bk + (size_t)l * NHEAD * HDIM;
    const float* bv_l = bv + (size_t)l * NHEAD * HDIM;
    const float* bo_l = bo + (size_t)l * EMB;

    for (int c = 0; c < BATCH / CHUNK; c++) {
      int b0 = c * CHUNK;
      kv_mfma_kernel<<<dim3(CHUNK * SEQ / 64, 2 * NHEAD * HDIM / 64), 256, 0,
                       stream>>>(hbf, wkvT_l, bk_l, bv_l, kbuf, vbufT, b0);
      attn_mfma_kernel<<<9 * NHEAD * CHUNK, 256, 0, stream>>>(
          hbf, wqT_l, bq_l, kbuf, vbufT, heads, b0);
    }
    // LN1: reads residual h, writes hA (fp32) + hbf (bf16)
    wo_ln_mfma_kernel<<<TOK / 64, 256, 0, stream>>>(
        heads, woT_l, bo_l, n1_g + l * EMB, n1_b + l * EMB, h, hA, hbf);
    // FF path (MFMA): ff1 reads hbf -> ffbf; ff2 reads ffbf + hA residual
    ff1_mfma_kernel<<<TOK / 64, 256, 0, stream>>>(hbf, ff1WT_l,
                                                  ff1_b + l * FFDIM, ffbf);
    float* dst = (l == NLAYER - 1) ? (float*)d_out : h;
    ff2_ln_mfma_kernel<<<TOK / 64, 256, 0, stream>>>(
        ffbf, ff2WT_l, ff2_b + l * EMB, n2_g + l * EMB, n2_b + l * EMB, hA,
        dst, hbf);
  }
}

// Round 14
// 1381.054 us; speedup vs baseline: 1.1692x; 1.0158x over previous
//
#include <hip/hip_runtime.h>
#include <hip/hip_bf16.h>
#include <math.h>

#define BATCH 64
#define CHUNK 32           // batch chunk for k/v scratch
#define INPUT_SIZE 10080
#define PATCH 18
#define SEQ 560            // S
#define EMB 96             // E
#define NHEAD 12           // H
#define HDIM 96            // D
#define FFDIM 256          // F
#define NLAYER 2
#define TOK (BATCH * SEQ)  // 35840 tokens
#define EPSV 1e-5f
#define SCALE 0.10206207261596577f  // 1/sqrt(96)

typedef __attribute__((ext_vector_type(8))) short bf16x8;  // 8 bf16 (4 VGPRs)
typedef __attribute__((ext_vector_type(4))) short bf16x4;  // 4 bf16 (8B store)
typedef __attribute__((ext_vector_type(4))) float f32x4;   // 4 fp32 acc

static __device__ __forceinline__ short f2bf(float x) {
  union { __hip_bfloat16 b; short s; } u;
  u.b = __float2bfloat16(x);
  return u.s;
}

// ---------------- Kernel 0: all weight transposes, one launch --------------
// bx in [0,72): wprep  (hh=bx%12, mat=(bx/12)%3, l=bx/36)
// bx in [72,74): woprep (l=bx-72)
// bx in [74,78): ffprep (idx=bx-74: mat=idx%2, l=idx/2)
__global__ __launch_bounds__(256) void allprep_kernel(
    const float* __restrict__ Wq, const float* __restrict__ Wk,
    const float* __restrict__ Wv, const float* __restrict__ Wo,
    const float* __restrict__ ff1_W, const float* __restrict__ ff2_W,
    __hip_bfloat16* __restrict__ wqT, __hip_bfloat16* __restrict__ wkvT,
    __hip_bfloat16* __restrict__ woT, __hip_bfloat16* __restrict__ ff1WT,
    __hip_bfloat16* __restrict__ ff2WT) {
  int bx = blockIdx.x;
  if (bx < 72) {
    int hh = bx % NHEAD, mat = (bx / NHEAD) % 3, l = bx / 36;
    const float* src = (mat == 0 ? Wq : (mat == 1 ? Wk : Wv)) +
                       ((size_t)l * NHEAD + hh) * EMB * HDIM;
    __shared__ float t[HDIM * 97];
    for (int i = threadIdx.x; i < EMB * HDIM; i += 256) {
      int e = i / HDIM, d = i % HDIM;
      t[d * 97 + e] = src[i];
    }
    __syncthreads();
    __hip_bfloat16* dst;
    if (mat == 0)
      dst = wqT + ((size_t)l * NHEAD + hh) * HDIM * EMB;
    else
      dst = wkvT + ((size_t)l * 2 * NHEAD * HDIM + (mat - 1) * NHEAD * HDIM +
                    hh * HDIM) * EMB;
    for (int j = threadIdx.x; j < HDIM * EMB; j += 256) {
      int d = j / EMB, e = j % EMB;
      dst[j] = __float2bfloat16(t[d * 97 + e]);
    }
  } else if (bx < 74) {
    int l = bx - 72;
    const float* src = Wo + (size_t)l * NHEAD * HDIM * EMB;
    __hip_bfloat16* dst = woT + (size_t)l * EMB * NHEAD * HDIM;
    for (int i = threadIdx.x; i < EMB * NHEAD * HDIM; i += 256) {
      int e = i / (NHEAD * HDIM), j = i % (NHEAD * HDIM);
      dst[i] = __float2bfloat16(src[(size_t)j * EMB + e]);
    }
  } else {
    int idx = bx - 74;
    int mat = idx % 2, l = idx / 2;
    if (mat == 0) {
      const float* src = ff1_W + (size_t)l * EMB * FFDIM;
      __hip_bfloat16* dst = ff1WT + (size_t)l * FFDIM * EMB;
      for (int i = threadIdx.x; i < FFDIM * EMB; i += 256) {
        int f = i / EMB, e = i % EMB;
        dst[i] = __float2bfloat16(src[(size_t)e * FFDIM + f]);
      }
    } else {
      const float* src = ff2_W + (size_t)l * FFDIM * EMB;
      __hip_bfloat16* dst = ff2WT + (size_t)l * EMB * FFDIM;
      for (int i = threadIdx.x; i < EMB * FFDIM; i += 256) {
        int e = i / FFDIM, f = i % FFDIM;
        dst[i] = __float2bfloat16(src[(size_t)f * EMB + e]);
      }
    }
  }
}

// ---------------- Kernel 1: patch embedding + sinusoidal PE ----------------
__global__ void patch_pe_kernel(const float* __restrict__ x,
                                const float* __restrict__ W,
                                const float* __restrict__ bias,
                                float* __restrict__ h,
                                __hip_bfloat16* __restrict__ hbf) {
  int gid = blockIdx.x * blockDim.x + threadIdx.x;
  if (gid >= TOK * EMB) return;
  int tok = gid / EMB;
  int e = gid % EMB;
  int b = tok / SEQ;
  int s = tok % SEQ;
  const float* xp = x + b * INPUT_SIZE + s * PATCH;
  float acc = bias[e];
#pragma unroll
  for (int p = 0; p < PATCH; p++) acc += xp[p] * W[p * EMB + e];
  int i = e >> 1;
  float freq = __expf(-(float)(2 * i) * (9.210340371976184f / 96.0f));
  float ang = (float)s * freq;
  acc += (e & 1) ? cosf(ang) : sinf(ang);
  h[gid] = acc;
  hbf[gid] = __float2bfloat16(acc);
}

// ---------------- Kernel 2: K/V projection GEMM (MFMA) ---------------------
// K half -> kbuf[bh][s][d] via wave-local LDS bounce -> coalesced 16B rows.
// V half -> vbufT[bh][d][t] via 8B packed stores.
__global__ __launch_bounds__(256) void kv_mfma_kernel(
    const __hip_bfloat16* __restrict__ hbf,
    const __hip_bfloat16* __restrict__ wkvT, const float* __restrict__ bk,
    const float* __restrict__ bv, __hip_bfloat16* __restrict__ kbuf,
    __hip_bfloat16* __restrict__ vbufT, int b0) {
  const int wave = threadIdx.x >> 6;
  const int lane = threadIdx.x & 63;
  const int tq = lane & 15;
  const int quad = lane >> 4;
  const int m0 = blockIdx.x * 64 + wave * 16;  // token tile row (chunk-local)
  const int n0 = blockIdx.y * 64;

  __shared__ short tile[4][16][68];  // wave-local K bounce (8.7 KB)

  const short* ap =
      (const short*)hbf + ((size_t)b0 * SEQ + m0 + tq) * EMB + quad * 8;
  bf16x8 a0 = *(const bf16x8*)(ap);
  bf16x8 a1 = *(const bf16x8*)(ap + 32);
  bf16x8 a2 = *(const bf16x8*)(ap + 64);

  f32x4 acc[4];
  const f32x4 zero4 = {0.f, 0.f, 0.f, 0.f};
#pragma unroll
  for (int nt = 0; nt < 4; nt++) acc[nt] = zero4;
#pragma unroll
  for (int nt = 0; nt < 4; nt++) {
    const short* bp =
        (const short*)wkvT + (size_t)(n0 + nt * 16 + tq) * EMB + quad * 8;
    bf16x8 b0f = *(const bf16x8*)(bp);
    bf16x8 b1f = *(const bf16x8*)(bp + 32);
    bf16x8 b2f = *(const bf16x8*)(bp + 64);
    acc[nt] = __builtin_amdgcn_mfma_f32_16x16x32_bf16(a0, b0f, acc[nt], 0, 0, 0);
    acc[nt] = __builtin_amdgcn_mfma_f32_16x16x32_bf16(a1, b1f, acc[nt], 0, 0, 0);
    acc[nt] = __builtin_amdgcn_mfma_f32_16x16x32_bf16(a2, b2f, acc[nt], 0, 0, 0);
  }

  const int tl0 = m0 + quad * 4;
  const int blb = tl0 / SEQ;
  const int ss0 = tl0 - blb * SEQ;

  if (n0 < NHEAD * HDIM) {
    // ---- K tile: bias -> LDS (wave-local) -> coalesced bf16x8 stores ----
#pragma unroll
    for (int nt = 0; nt < 4; nt++) {
      int n = n0 + nt * 16 + tq;
      float bias = bk[n];
#pragma unroll
      for (int j = 0; j < 4; j++)
        tile[wave][quad * 4 + j][nt * 16 + tq] = f2bf(acc[nt][j] + bias);
    }
#pragma unroll
    for (int it = 0; it < 2; it++) {
      int idx = it * 64 + lane;
      int row = idx >> 3;
      int seg = idx & 7;
      int tl = m0 + row;
      int bb = tl / SEQ;
      int ss = tl - bb * SEQ;
      int r0s = n0 + seg * 8;
      int hh2 = r0s / HDIM;
      int d0 = r0s - hh2 * HDIM;
      bf16x8 v = *(const bf16x8*)&tile[wave][row][seg * 8];
      *(bf16x8*)((short*)kbuf +
                 ((size_t)(bb * NHEAD + hh2) * SEQ + ss) * HDIM + d0) = v;
    }
  } else {
    // ---- V tile: packed 8B stores into vbufT[bh][d][t] ----
#pragma unroll
    for (int nt = 0; nt < 4; nt++) {
      int n = n0 + nt * 16 + tq;
      int r = n - NHEAD * HDIM;
      int hh2 = r / HDIM;
      int d = r - hh2 * HDIM;
      float bias = bv[r];
      bf16x4 pack;
#pragma unroll
      for (int j = 0; j < 4; j++) pack[j] = f2bf(acc[nt][j] + bias);
      *(bf16x4*)((short*)vbufT +
                 ((size_t)(blb * NHEAD + hh2) * HDIM + d) * SEQ + ss0) = pack;
    }
  }
}

// ---------------- Kernel 3: MFMA attention with LDS K staging (frozen) -----
#define PSTRIDE 584  // Q/P view row stride (shorts)
#define KSTR 104     // K view row stride (shorts): 208B, 16B-aligned
__global__ __launch_bounds__(256, 2) void attn_mfma_kernel(
    const __hip_bfloat16* __restrict__ hbf,
    const __hip_bfloat16* __restrict__ wqT, const float* __restrict__ bq,
    const __hip_bfloat16* __restrict__ kbuf,
    const __hip_bfloat16* __restrict__ vbufT,
    __hip_bfloat16* __restrict__ heads, int b0) {
  const int flat = blockIdx.x;
  const int xcd = flat & 7;
  const int slot = flat >> 3;
  const int g = (slot / 9) * 8 + xcd;  // 0..383 group = (bl,hh)
  const int qt = slot % 9;             // 0..8
  const int hh = g % NHEAD;
  const int bl = g / NHEAD;            // local batch 0..31
  const int wave = threadIdx.x >> 6;
  const int lane = threadIdx.x & 63;
  const int tq = lane & 15;
  const int quad = lane >> 4;

  __shared__ __align__(16) short sbuf[4 * 16 * PSTRIDE];  // 74752 B
  short* pw = sbuf + wave * 16 * PSTRIDE;  // wave's Q/P region [16][PSTRIDE]

  const size_t bh = (size_t)(bl * NHEAD + hh);
  const short* kb = (const short*)kbuf + bh * SEQ * HDIM;
  const short* vb = (const short*)vbufT + bh * HDIM * SEQ;

  // ---- (1) Q projection via MFMA: 16 q rows x 96 d ----
  const int q0 = qt * 64 + wave * 16;
  int qrow = q0 + tq;
  if (qrow > SEQ - 1) qrow = SEQ - 1;
  const short* hp =
      (const short*)hbf + ((size_t)(b0 + bl) * SEQ + qrow) * EMB + quad * 8;
  bf16x8 ha0 = *(const bf16x8*)(hp);
  bf16x8 ha1 = *(const bf16x8*)(hp + 32);
  bf16x8 ha2 = *(const bf16x8*)(hp + 64);
  const f32x4 zero4 = {0.f, 0.f, 0.f, 0.f};
  f32x4 qacc[6];
#pragma unroll
  for (int dt = 0; dt < 6; dt++) qacc[dt] = zero4;
#pragma unroll
  for (int dt = 0; dt < 6; dt++) {
    const short* wp = (const short*)wqT +
                      ((size_t)hh * HDIM + dt * 16 + tq) * EMB + quad * 8;
    bf16x8 w0 = *(const bf16x8*)(wp);
    bf16x8 w1 = *(const bf16x8*)(wp + 32);
    bf16x8 w2 = *(const bf16x8*)(wp + 64);
    qacc[dt] = __builtin_amdgcn_mfma_f32_16x16x32_bf16(ha0, w0, qacc[dt], 0, 0, 0);
    qacc[dt] = __builtin_amdgcn_mfma_f32_16x16x32_bf16(ha1, w1, qacc[dt], 0, 0, 0);
    qacc[dt] = __builtin_amdgcn_mfma_f32_16x16x32_bf16(ha2, w2, qacc[dt], 0, 0, 0);
  }
#pragma unroll
  for (int dt = 0; dt < 6; dt++) {
    int d = dt * 16 + tq;
    float bias = bq[hh * HDIM + d];
#pragma unroll
    for (int r = 0; r < 4; r++)
      pw[(quad * 4 + r) * PSTRIDE + d] = f2bf((qacc[dt][r] + bias) * SCALE);
  }
  bf16x8 aq0 = *(const bf16x8*)&pw[tq * PSTRIDE + quad * 8];
  bf16x8 aq1 = *(const bf16x8*)&pw[tq * PSTRIDE + quad * 8 + 32];
  bf16x8 aq2 = *(const bf16x8*)&pw[tq * PSTRIDE + quad * 8 + 64];
  __syncthreads();  // all waves have Q in regs; sbuf free for K staging

  f32x4 acc[35];
#pragma unroll
  for (int tt = 0; tt < 35; tt++) acc[tt] = zero4;

  // ---- (2a) stage K rows [0,288) and compute score tiles 0..17 ----
  for (int i = threadIdx.x; i < 288 * 12; i += 256) {
    int row = i / 12, gg = i - row * 12;
    *(bf16x8*)&sbuf[row * KSTR + gg * 8] =
        *(const bf16x8*)(kb + (size_t)row * HDIM + gg * 8);
  }
  __syncthreads();
#pragma unroll
  for (int tt = 0; tt < 18; tt++) {
    const short* kp = &sbuf[(tt * 16 + tq) * KSTR + quad * 8];
    bf16x8 kb0 = *(const bf16x8*)(kp);
    bf16x8 kb1 = *(const bf16x8*)(kp + 32);
    bf16x8 kb2 = *(const bf16x8*)(kp + 64);
    acc[tt] = __builtin_amdgcn_mfma_f32_16x16x32_bf16(aq0, kb0, acc[tt], 0, 0, 0);
    acc[tt] = __builtin_amdgcn_mfma_f32_16x16x32_bf16(aq1, kb1, acc[tt], 0, 0, 0);
    acc[tt] = __builtin_amdgcn_mfma_f32_16x16x32_bf16(aq2, kb2, acc[tt], 0, 0, 0);
  }
  __syncthreads();

  // ---- (2b) stage K rows [288,560) and compute score tiles 18..34 ----
  for (int i = threadIdx.x; i < 272 * 12; i += 256) {
    int row = i / 12, gg = i - row * 12;
    *(bf16x8*)&sbuf[row * KSTR + gg * 8] =
        *(const bf16x8*)(kb + (size_t)(288 + row) * HDIM + gg * 8);
  }
  __syncthreads();
#pragma unroll
  for (int tt = 18; tt < 35; tt++) {
    const short* kp = &sbuf[(tt * 16 + tq - 288) * KSTR + quad * 8];
    bf16x8 kb0 = *(const bf16x8*)(kp);
    bf16x8 kb1 = *(const bf16x8*)(kp + 32);
    bf16x8 kb2 = *(const bf16x8*)(kp + 64);
    acc[tt] = __builtin_amdgcn_mfma_f32_16x16x32_bf16(aq0, kb0, acc[tt], 0, 0, 0);
    acc[tt] = __builtin_amdgcn_mfma_f32_16x16x32_bf16(aq1, kb1, acc[tt], 0, 0, 0);
    acc[tt] = __builtin_amdgcn_mfma_f32_16x16x32_bf16(aq2, kb2, acc[tt], 0, 0, 0);
  }

  // ---- softmax ----
  float m0 = -1e30f, m1 = -1e30f, m2 = -1e30f, m3 = -1e30f;
#pragma unroll
  for (int tt = 0; tt < 35; tt++) {
    m0 = fmaxf(m0, acc[tt][0]);
    m1 = fmaxf(m1, acc[tt][1]);
    m2 = fmaxf(m2, acc[tt][2]);
    m3 = fmaxf(m3, acc[tt][3]);
  }
#pragma unroll
  for (int mask = 1; mask < 16; mask <<= 1) {
    m0 = fmaxf(m0, __shfl_xor(m0, mask, 64));
    m1 = fmaxf(m1, __shfl_xor(m1, mask, 64));
    m2 = fmaxf(m2, __shfl_xor(m2, mask, 64));
    m3 = fmaxf(m3, __shfl_xor(m3, mask, 64));
  }
  float l0 = 0.f, l1 = 0.f, l2 = 0.f, l3 = 0.f;
#pragma unroll
  for (int tt = 0; tt < 35; tt++) {
    float p0 = __expf(acc[tt][0] - m0); acc[tt][0] = p0; l0 += p0;
    float p1 = __expf(acc[tt][1] - m1); acc[tt][1] = p1; l1 += p1;
    float p2 = __expf(acc[tt][2] - m2); acc[tt][2] = p2; l2 += p2;
    float p3 = __expf(acc[tt][3] - m3); acc[tt][3] = p3; l3 += p3;
  }
#pragma unroll
  for (int mask = 1; mask < 16; mask <<= 1) {
    l0 += __shfl_xor(l0, mask, 64);
    l1 += __shfl_xor(l1, mask, 64);
    l2 += __shfl_xor(l2, mask, 64);
    l3 += __shfl_xor(l3, mask, 64);
  }
  __syncthreads();  // all waves done reading K from sbuf

  // ---- (3) P -> pw (A-layout, unnormalized; wave-local) ----
  for (int i = lane; i < 256; i += 64)
    pw[(i >> 4) * PSTRIDE + 560 + (i & 15)] = 0;
#pragma unroll
  for (int tt = 0; tt < 35; tt++) {
    int col = tt * 16 + tq;
    pw[(quad * 4 + 0) * PSTRIDE + col] = f2bf(acc[tt][0]);
    pw[(quad * 4 + 1) * PSTRIDE + col] = f2bf(acc[tt][1]);
    pw[(quad * 4 + 2) * PSTRIDE + col] = f2bf(acc[tt][2]);
    pw[(quad * 4 + 3) * PSTRIDE + col] = f2bf(acc[tt][3]);
  }

  // ---- PV (wave-local) ----
  f32x4 oacc[6];
#pragma unroll
  for (int dt = 0; dt < 6; dt++) oacc[dt] = zero4;
#pragma unroll
  for (int kt = 0; kt < 18; kt++) {
    bf16x8 pa = *(const bf16x8*)&pw[tq * PSTRIDE + kt * 32 + quad * 8];
#pragma unroll
    for (int dt = 0; dt < 6; dt++) {
      const short* vp = vb + (size_t)(dt * 16 + tq) * SEQ + kt * 32 + quad * 8;
      bf16x8 vf = *(const bf16x8*)vp;
      oacc[dt] = __builtin_amdgcn_mfma_f32_16x16x32_bf16(pa, vf, oacc[dt], 0, 0, 0);
    }
  }

  // ---- normalize + store ----
  float r0 = 1.f / l0, r1 = 1.f / l1, r2 = 1.f / l2, r3 = 1.f / l3;
  int qg = q0 + quad * 4;
  __hip_bfloat16* hpout =
      heads + ((size_t)(b0 + bl) * SEQ) * (NHEAD * HDIM) + (size_t)hh * HDIM;
#pragma unroll
  for (int dt = 0; dt < 6; dt++) {
    int d = dt * 16 + tq;
    if (qg + 0 < SEQ) hpout[(size_t)(qg + 0) * (NHEAD * HDIM) + d] = __float2bfloat16(oacc[dt][0] * r0);
    if (qg + 1 < SEQ) hpout[(size_t)(qg + 1) * (NHEAD * HDIM) + d] = __float2bfloat16(oacc[dt][1] * r1);
    if (qg + 2 < SEQ) hpout[(size_t)(qg + 2) * (NHEAD * HDIM) + d] = __float2bfloat16(oacc[dt][2] * r2);
    if (qg + 3 < SEQ) hpout[(size_t)(qg + 3) * (NHEAD * HDIM) + d] = __float2bfloat16(oacc[dt][3] * r3);
  }
}

// ---------------- Kernel 4: Wo GEMM + residual + LayerNorm (MFMA, proven) --
__global__ __launch_bounds__(256) void wo_ln_mfma_kernel(
    const __hip_bfloat16* __restrict__ heads,
    const __hip_bfloat16* __restrict__ woT, const float* __restrict__ bo,
    const float* __restrict__ gamma, const float* __restrict__ beta,
    const float* __restrict__ hres, float* __restrict__ hA,
    __hip_bfloat16* __restrict__ hbf) {
  const int wave = threadIdx.x >> 6;
  const int lane = threadIdx.x & 63;
  const int tq = lane & 15;
  const int quad = lane >> 4;
  const int m0 = blockIdx.x * 64 + wave * 16;

  const short* ap = (const short*)heads + (size_t)(m0 + tq) * (NHEAD * HDIM);
  const short* bp = (const short*)woT;

  f32x4 acc[6];
  const f32x4 zero4 = {0.f, 0.f, 0.f, 0.f};
#pragma unroll
  for (int dt = 0; dt < 6; dt++) acc[dt] = zero4;

  for (int kt = 0; kt < 36; kt++) {
    bf16x8 af = *(const bf16x8*)(ap + kt * 32 + quad * 8);
#pragma unroll
    for (int dt = 0; dt < 6; dt++) {
      bf16x8 bfr = *(const bf16x8*)(bp + (size_t)(dt * 16 + tq) * (NHEAD * HDIM) +
                                    kt * 32 + quad * 8);
      acc[dt] = __builtin_amdgcn_mfma_f32_16x16x32_bf16(af, bfr, acc[dt], 0, 0, 0);
    }
  }

  const int tok0 = m0 + quad * 4;
  float s1[4] = {0.f, 0.f, 0.f, 0.f};
  float s2[4] = {0.f, 0.f, 0.f, 0.f};
#pragma unroll
  for (int dt = 0; dt < 6; dt++) {
    int n = dt * 16 + tq;
    float bias = bo[n];
#pragma unroll
    for (int r = 0; r < 4; r++) {
      float val = acc[dt][r] + bias + hres[(size_t)(tok0 + r) * EMB + n];
      acc[dt][r] = val;
      s1[r] += val;
      s2[r] += val * val;
    }
  }
#pragma unroll
  for (int mask = 1; mask < 16; mask <<= 1) {
#pragma unroll
    for (int r = 0; r < 4; r++) {
      s1[r] += __shfl_xor(s1[r], mask, 64);
      s2[r] += __shfl_xor(s2[r], mask, 64);
    }
  }
  float mean[4], rstd[4];
#pragma unroll
  for (int r = 0; r < 4; r++) {
    mean[r] = s1[r] * (1.0f / EMB);
    float var = s2[r] * (1.0f / EMB) - mean[r] * mean[r];
    rstd[r] = rsqrtf(var + EPSV);
  }
#pragma unroll
  for (int dt = 0; dt < 6; dt++) {
    int n = dt * 16 + tq;
    float g = gamma[n], bt = beta[n];
#pragma unroll
    for (int r = 0; r < 4; r++) {
      float o = (acc[dt][r] - mean[r]) * rstd[r] * g + bt;
      hA[(size_t)(tok0 + r) * EMB + n] = o;
      hbf[(size_t)(tok0 + r) * EMB + n] = __float2bfloat16(o);
    }
  }
}

// ---------------- Kernel 5: FF1 GEMM + ReLU (MFMA, proven) -----------------
__global__ __launch_bounds__(256) void ff1_mfma_kernel(
    const __hip_bfloat16* __restrict__ hbf,
    const __hip_bfloat16* __restrict__ ff1WT, const float* __restrict__ b1,
    __hip_bfloat16* __restrict__ ffbf) {
  const int wave = threadIdx.x >> 6;
  const int lane = threadIdx.x & 63;
  const int tq = lane & 15;
  const int quad = lane >> 4;
  const int m0 = blockIdx.x * 64 + wave * 16;

  const short* ap = (const short*)hbf + (size_t)(m0 + tq) * EMB + quad * 8;
  bf16x8 a0 = *(const bf16x8*)(ap);
  bf16x8 a1 = *(const bf16x8*)(ap + 32);
  bf16x8 a2 = *(const bf16x8*)(ap + 64);

  f32x4 acc[16];
  const f32x4 zero4 = {0.f, 0.f, 0.f, 0.f};
#pragma unroll
  for (int nt = 0; nt < 16; nt++) acc[nt] = zero4;
#pragma unroll
  for (int nt = 0; nt < 16; nt++) {
    const short* bp =
        (const short*)ff1WT + (size_t)(nt * 16 + tq) * EMB + quad * 8;
    bf16x8 b0f = *(const bf16x8*)(bp);
    bf16x8 b1f = *(const bf16x8*)(bp + 32);
    bf16x8 b2f = *(const bf16x8*)(bp + 64);
    acc[nt] = __builtin_amdgcn_mfma_f32_16x16x32_bf16(a0, b0f, acc[nt], 0, 0, 0);
    acc[nt] = __builtin_amdgcn_mfma_f32_16x16x32_bf16(a1, b1f, acc[nt], 0, 0, 0);
    acc[nt] = __builtin_amdgcn_mfma_f32_16x16x32_bf16(a2, b2f, acc[nt], 0, 0, 0);
  }

  const int tok0 = m0 + quad * 4;
#pragma unroll
  for (int nt = 0; nt < 16; nt++) {
    int n = nt * 16 + tq;
    float bias = b1[n];
#pragma unroll
    for (int r = 0; r < 4; r++) {
      ffbf[(size_t)(tok0 + r) * FFDIM + n] =
          __float2bfloat16(fmaxf(acc[nt][r] + bias, 0.f));
    }
  }
}

// ---------------- Kernel 6: FF2 GEMM + residual + LN (MFMA, proven) --------
__global__ __launch_bounds__(256) void ff2_ln_mfma_kernel(
    const __hip_bfloat16* __restrict__ ffbf,
    const __hip_bfloat16* __restrict__ ff2WT, const float* __restrict__ b2,
    const float* __restrict__ gamma, const float* __restrict__ beta,
    const float* __restrict__ hres, float* __restrict__ hout,
    __hip_bfloat16* __restrict__ hbf_out) {
  const int wave = threadIdx.x >> 6;
  const int lane = threadIdx.x & 63;
  const int tq = lane & 15;
  const int quad = lane >> 4;
  const int m0 = blockIdx.x * 64 + wave * 16;

  const short* ap = (const short*)ffbf + (size_t)(m0 + tq) * FFDIM;
  const short* bp = (const short*)ff2WT;

  f32x4 acc[6];
  const f32x4 zero4 = {0.f, 0.f, 0.f, 0.f};
#pragma unroll
  for (int dt = 0; dt < 6; dt++) acc[dt] = zero4;

#pragma unroll
  for (int kt = 0; kt < 8; kt++) {
    bf16x8 af = *(const bf16x8*)(ap + kt * 32 + quad * 8);
#pragma unroll
    for (int dt = 0; dt < 6; dt++) {
      bf16x8 bfr = *(const bf16x8*)(bp + (size_t)(dt * 16 + tq) * FFDIM +
                                    kt * 32 + quad * 8);
      acc[dt] = __builtin_amdgcn_mfma_f32_16x16x32_bf16(af, bfr, acc[dt], 0, 0, 0);
    }
  }

  const int tok0 = m0 + quad * 4;
  float s1[4] = {0.f, 0.f, 0.f, 0.f};
  float s2[4] = {0.f, 0.f, 0.f, 0.f};
#pragma unroll
  for (int dt = 0; dt < 6; dt++) {
    int n = dt * 16 + tq;
    float bias = b2[n];
#pragma unroll
    for (int r = 0; r < 4; r++) {
      float val = acc[dt][r] + bias + hres[(size_t)(tok0 + r) * EMB + n];
      acc[dt][r] = val;
      s1[r] += val;
      s2[r] += val * val;
    }
  }
#pragma unroll
  for (int mask = 1; mask < 16; mask <<= 1) {
#pragma unroll
    for (int r = 0; r < 4; r++) {
      s1[r] += __shfl_xor(s1[r], mask, 64);
      s2[r] += __shfl_xor(s2[r], mask, 64);
    }
  }
  float mean[4], rstd[4];
#pragma unroll
  for (int r = 0; r < 4; r++) {
    mean[r] = s1[r] * (1.0f / EMB);
    float var = s2[r] * (1.0f / EMB) - mean[r] * mean[r];
    rstd[r] = rsqrtf(var + EPSV);
  }
#pragma unroll
  for (int dt = 0; dt < 6; dt++) {
    int n = dt * 16 + tq;
    float g = gamma[n], bt = beta[n];
#pragma unroll
    for (int r = 0; r < 4; r++) {
      float o = (acc[dt][r] - mean[r]) * rstd[r] * g + bt;
      hout[(size_t)(tok0 + r) * EMB + n] = o;
      hbf_out[(size_t)(tok0 + r) * EMB + n] = __float2bfloat16(o);
    }
  }
}

// ---------------- launch ----------------------------------------------------
extern "C" void kernel_launch(void* const* d_in, const int* in_sizes, int n_in,
                              void* d_out, int out_size, void* d_ws,
                              size_t ws_size, hipStream_t stream) {
  const float* x = (const float*)d_in[0];
  const float* patch_W = (const float*)d_in[1];
  const float* patch_b = (const float*)d_in[2];
  const float* Wq = (const float*)d_in[3];
  const float* bq = (const float*)d_in[4];
  const float* Wk = (const float*)d_in[5];
  const float* bk = (const float*)d_in[6];
  const float* Wv = (const float*)d_in[7];
  const float* bv = (const float*)d_in[8];
  const float* Wo = (const float*)d_in[9];
  const float* bo = (const float*)d_in[10];
  const float* ff1_W = (const float*)d_in[11];
  const float* ff1_b = (const float*)d_in[12];
  const float* ff2_W = (const float*)d_in[13];
  const float* ff2_b = (const float*)d_in[14];
  const float* n1_g = (const float*)d_in[15];
  const float* n1_b = (const float*)d_in[16];
  const float* n2_g = (const float*)d_in[17];
  const float* n2_b = (const float*)d_in[18];

  // workspace layout (~202 MB)
  const size_t h_bytes = (size_t)TOK * EMB * sizeof(float);          // 13.76 MB
  const size_t hbf_bytes = (size_t)TOK * EMB * 2;                    // 6.88 MB
  const size_t kv_bytes = (size_t)CHUNK * NHEAD * SEQ * HDIM * 2;    // 41.29 MB
  const size_t heads_bytes = (size_t)TOK * NHEAD * HDIM * 2;         // 82.58 MB
  const size_t wqT_bytes = (size_t)NLAYER * NHEAD * HDIM * EMB * 2;  // 0.44 MB
  const size_t wkvT_bytes = 2 * wqT_bytes;                           // 0.88 MB
  const size_t woT_bytes = (size_t)NLAYER * EMB * NHEAD * HDIM * 2;  // 0.44 MB
  const size_t ffw_bytes = (size_t)NLAYER * FFDIM * EMB * 2;         // 0.10 MB
  char* ws = (char*)d_ws;
  size_t off = 0;
  float* h = (float*)(ws + off); off += h_bytes;
  float* hA = (float*)(ws + off); off += h_bytes;
  __hip_bfloat16* hbf = (__hip_bfloat16*)(ws + off); off += hbf_bytes;
  __hip_bfloat16* kbuf = (__hip_bfloat16*)(ws + off); off += kv_bytes;
  __hip_bfloat16* vbufT = (__hip_bfloat16*)(ws + off); off += kv_bytes;
  __hip_bfloat16* heads = (__hip_bfloat16*)(ws + off); off += heads_bytes;
  __hip_bfloat16* wqT = (__hip_bfloat16*)(ws + off); off += wqT_bytes;
  __hip_bfloat16* wkvT = (__hip_bfloat16*)(ws + off); off += wkvT_bytes;
  __hip_bfloat16* woT = (__hip_bfloat16*)(ws + off); off += woT_bytes;
  __hip_bfloat16* ff1WT = (__hip_bfloat16*)(ws + off); off += ffw_bytes;
  __hip_bfloat16* ff2WT = (__hip_bfloat16*)(ws + off); off += ffw_bytes;
  __hip_bfloat16* ffbf = (__hip_bfloat16*)kbuf;  // alias: free after attention

  allprep_kernel<<<78, 256, 0, stream>>>(Wq, Wk, Wv, Wo, ff1_W, ff2_W, wqT,
                                         wkvT, woT, ff1WT, ff2WT);
  patch_pe_kernel<<<(TOK * EMB + 255) / 256, 256, 0, stream>>>(x, patch_W,
                                                               patch_b, h, hbf);

  for (int l = 0; l < NLAYER; l++) {
    const __hip_bfloat16* wqT_l = wqT + (size_t)l * NHEAD * HDIM * EMB;
    const __hip_bfloat16* wkvT_l = wkvT + (size_t)l * 2 * NHEAD * HDIM * EMB;
    const __hip_bfloat16* woT_l = woT + (size_t)l * EMB * NHEAD * HDIM;
    const __hip_bfloat16* ff1WT_l = ff1WT + (size_t)l * FFDIM * EMB;
    const __hip_bfloat16* ff2WT_l = ff2WT + (size_t)l * EMB * FFDIM;
    const float* bq_l = bq + (size_t)l * NHEAD * HDIM;
    const float* bk_l = bk + (size_t)l * NHEAD * HDIM;
    const float* bv_l = bv + (size_t)l * NHEAD * HDIM;
    const float* bo_l = bo + (size_t)l * EMB;

    for (int c = 0; c < BATCH / CHUNK; c++) {
      int b0 = c * CHUNK;
      kv_mfma_kernel<<<dim3(CHUNK * SEQ / 64, 2 * NHEAD * HDIM / 64), 256, 0,
                       stream>>>(hbf, wkvT_l, bk_l, bv_l, kbuf, vbufT, b0);
      attn_mfma_kernel<<<9 * NHEAD * CHUNK, 256, 0, stream>>>(
          hbf, wqT_l, bq_l, kbuf, vbufT, heads, b0);
    }
    // LN1: reads residual h, writes hA (fp32) + hbf (bf16)
    wo_ln_mfma_kernel<<<TOK / 64, 256, 0, stream>>>(
        heads, woT_l, bo_l, n1_g + l * EMB, n1_b + l * EMB, h, hA, hbf);
    // FF path (MFMA, split, proven): ff1 reads hbf -> ffbf; ff2 reads ffbf + hA
    ff1_mfma_kernel<<<TOK / 64, 256, 0, stream>>>(hbf, ff1WT_l,
                                                  ff1_b + l * FFDIM, ffbf);
    float* dst = (l == NLAYER - 1) ? (float*)d_out : h;
    ff2_ln_mfma_kernel<<<TOK / 64, 256, 0, stream>>>(
        ffbf, ff2WT_l, ff2_b + l * EMB, n2_g + l * EMB, n2_b + l * EMB, hA,
        dst, hbf);
  }
}